// Round 4
// baseline (941.962 us; speedup 1.0000x reference)
//
#include <hip/hip_runtime.h>

#define N_NODES 50000
#define N_EDGES 500000
#define EB 64
#define KP1 200          // A row stride (bf16 elems)
#define KH  136          // H row stride
#define KV  104          // VS row stride
#define WTS 40           // Wt row stride
#define OUTC 320
#define MIXROWS 500032   // 7813 * 64
#define NBLK1 49         // ceil(50000/1024) scan level-1 blocks
#define INV_SQ3 0.57735026918962576f
#define INV_SQ2 0.70710678118654752f
#define INV_AVG 0.1f

typedef short bf16x8 __attribute__((ext_vector_type(8)));
typedef unsigned short u16;
typedef u16 u16x8 __attribute__((ext_vector_type(8)));
typedef float f32x16 __attribute__((ext_vector_type(16)));

__device__ __forceinline__ float bf2f(u16 h) {
    union { unsigned u; float f; } x; x.u = ((unsigned)h) << 16; return x.f;
}
__device__ __forceinline__ u16 f2bf(float f) {   // RNE
    unsigned u = __builtin_bit_cast(unsigned, f);
    u += 0x7FFFu + ((u >> 16) & 1u);
    return (u16)(u >> 16);
}
__device__ __forceinline__ float fsilu(float x) {
    return x * __builtin_amdgcn_rcpf(1.f + __expf(-x));
}

__device__ __forceinline__ void stage16(const float* g, u16* l, bool v) {
    float4 a0, a1, a2, a3;
    const float4 z = make_float4(0.f, 0.f, 0.f, 0.f);
    if (v) { a0 = *(const float4*)(g);     a1 = *(const float4*)(g + 4);
             a2 = *(const float4*)(g + 8); a3 = *(const float4*)(g + 12); }
    else   { a0 = z; a1 = z; a2 = z; a3 = z; }
    u16x8 p0 = { f2bf(a0.x), f2bf(a0.y), f2bf(a0.z), f2bf(a0.w),
                 f2bf(a1.x), f2bf(a1.y), f2bf(a1.z), f2bf(a1.w) };
    u16x8 p1 = { f2bf(a2.x), f2bf(a2.y), f2bf(a2.z), f2bf(a2.w),
                 f2bf(a3.x), f2bf(a3.y), f2bf(a3.z), f2bf(a3.w) };
    *(u16x8*)(l) = p0; *(u16x8*)(l + 8) = p1;
}
__device__ __forceinline__ void stage8(const float* g, u16* l, bool v) {
    float4 a0, a1;
    const float4 z = make_float4(0.f, 0.f, 0.f, 0.f);
    if (v) { a0 = *(const float4*)(g); a1 = *(const float4*)(g + 4); }
    else   { a0 = z; a1 = z; }
    u16x8 p0 = { f2bf(a0.x), f2bf(a0.y), f2bf(a0.z), f2bf(a0.w),
                 f2bf(a1.x), f2bf(a1.y), f2bf(a1.z), f2bf(a1.w) };
    *(u16x8*)(l) = p0;
}

// ==================== CSR build ====================

__global__ void hist_kernel(const int* __restrict__ recv, int* __restrict__ counts) {
    const int e = blockIdx.x * 256 + threadIdx.x;
    if (e < N_EDGES) atomicAdd(&counts[recv[e]], 1);
}

__global__ __launch_bounds__(256) void scan_k1(const int* __restrict__ counts,
                                               int* __restrict__ rowp,
                                               int* __restrict__ partials) {
    __shared__ int sd[256];
    const int t = threadIdx.x;
    const int base = blockIdx.x * 1024 + t * 4;
    int c0 = 0, c1 = 0, c2 = 0, c3 = 0;
    if (base + 3 < N_NODES) {
        int4 v = *(const int4*)&counts[base];
        c0 = v.x; c1 = v.y; c2 = v.z; c3 = v.w;
    } else {
        if (base     < N_NODES) c0 = counts[base];
        if (base + 1 < N_NODES) c1 = counts[base + 1];
        if (base + 2 < N_NODES) c2 = counts[base + 2];
        if (base + 3 < N_NODES) c3 = counts[base + 3];
    }
    const int T = c0 + c1 + c2 + c3;
    sd[t] = T; __syncthreads();
    for (int off = 1; off < 256; off <<= 1) {
        int v = (t >= off) ? sd[t - off] : 0;
        __syncthreads();
        sd[t] += v;
        __syncthreads();
    }
    const int excl = sd[t] - T;
    if (base     < N_NODES) rowp[base]     = excl;
    if (base + 1 < N_NODES) rowp[base + 1] = excl + c0;
    if (base + 2 < N_NODES) rowp[base + 2] = excl + c0 + c1;
    if (base + 3 < N_NODES) rowp[base + 3] = excl + c0 + c1 + c2;
    if (t == 255) partials[blockIdx.x] = sd[255];
}

__global__ __launch_bounds__(64) void scan_k2(int* __restrict__ partials) {
    __shared__ int sd[64];
    const int t = threadIdx.x;
    const int v0 = (t < NBLK1) ? partials[t] : 0;
    sd[t] = v0; __syncthreads();
    for (int off = 1; off < 64; off <<= 1) {
        int v = (t >= off) ? sd[t - off] : 0;
        __syncthreads();
        sd[t] += v;
        __syncthreads();
    }
    if (t < NBLK1) partials[t] = sd[t] - v0;
}

__global__ __launch_bounds__(256) void scan_k3(int* __restrict__ rowp,
                                               const int* __restrict__ partials,
                                               int* __restrict__ cursors) {
    const int add = partials[blockIdx.x];
    const int base = blockIdx.x * 1024 + threadIdx.x * 4;
    #pragma unroll
    for (int i = 0; i < 4; ++i) {
        const int idx = base + i;
        if (idx < N_NODES) {
            const int v = rowp[idx] + add;
            rowp[idx] = v;
            cursors[idx] = v;
        }
    }
    if (blockIdx.x == 0 && threadIdx.x == 0) rowp[N_NODES] = N_EDGES;
}

__global__ void fill_kernel(const int* __restrict__ recv,
                            int* __restrict__ cursors, int* __restrict__ elist) {
    const int e = blockIdx.x * 256 + threadIdx.x;
    if (e < N_EDGES) {
        const int r = recv[e];
        const int pos = atomicAdd(&cursors[r], 1);
        elist[pos] = e;
    }
}

// ==================== phase E: fused MLP (+ optional message epilogue) ====================
// MSG=true : writes full per-edge messages msg[e][320] (bf16)
// MSG=false: writes mix[e][128] (bf16)  (fallback v1 path)

template <bool MSG>
__global__ __launch_bounds__(256, 2)
void mlp_phase_kernel(const float* __restrict__ node_scalars,
                      const float* __restrict__ node_vectors,
                      const float* __restrict__ edge_vec,
                      const float* __restrict__ sef,
                      const float* __restrict__ lengths,
                      const int* __restrict__ senders,
                      const int* __restrict__ receivers,
                      const float* __restrict__ W1, const float* __restrict__ b1,
                      const float* __restrict__ W2, const float* __restrict__ b2,
                      const float* __restrict__ W3, const float* __restrict__ b3,
                      u16* __restrict__ outws)
{
    __shared__ u16 A [EB * KP1];
    __shared__ u16 VS[EB * KV];
    __shared__ u16 Hb[EB * KH];
    __shared__ u16 Wt[2][128 * WTS];
    __shared__ float evl[3][EB];
    __shared__ int sidx[EB], ridx[EB];

    const int t = threadIdx.x;
    const int ebase = blockIdx.x * EB;

    {   const int e = t & 63, sub = t >> 6;
        const int eg = ebase + e; const bool ve = eg < N_EDGES;
        if (sub == 0)      sidx[e] = ve ? senders[eg] : 0;
        else if (sub == 1) ridx[e] = ve ? receivers[eg] : 0;
        else if (sub == 2 && MSG) {
            evl[0][e] = ve ? edge_vec[(size_t)eg * 3 + 0] : 0.f;
            evl[1][e] = ve ? edge_vec[(size_t)eg * 3 + 1] : 0.f;
            evl[2][e] = ve ? edge_vec[(size_t)eg * 3 + 2] : 0.f;
        }
    }
    __syncthreads();

    {   const int me = t >> 2, q = t & 3;
        const int eg = ebase + me; const bool ve = eg < N_EDGES;
        const int si = sidx[me], ri = ridx[me];
        u16* Ar = A + me * KP1;
        stage16(node_scalars + (size_t)si * 64 + q * 16, Ar + q * 16,       ve);
        stage16(node_scalars + (size_t)ri * 64 + q * 16, Ar + 64 + q * 16,  ve);
        stage8 (sef          + (size_t)eg * 32 + q * 8,  Ar + 128 + q * 8,  ve);
        u16x8 zz = (u16x8)0;
        *(u16x8*)(Ar + 160 + q * 8) = zz;
        if (q == 0) *(u16x8*)(Ar + 192) = zz;
        if (MSG) {
            stage16(node_vectors + (size_t)si * 96 + q * 24,      VS + me * KV + q * 24,      ve);
            stage8 (node_vectors + (size_t)si * 96 + q * 24 + 16, VS + me * KV + q * 24 + 16, ve);
        }
        if (q == 0) Ar[160] = f2bf(ve ? lengths[eg] : 0.f);
    }
    __syncthreads();

    const int w  = t >> 6, l = t & 63;
    const int lr = l & 31;
    const int lg = l >> 5;
    const int m0 = (w >> 1) * 32;
    const int n0 = (w & 1) * 64;

    f32x16 acc0, acc1;
    const int n  = t & 127, ph = t >> 7;

    auto run_layer = [&](const u16* Asrc, int astr, const float* Wg, int Kr, int nsteps,
                         f32x16& a0, f32x16& a1) {
        #pragma unroll
        for (int i = 0; i < 16; ++i) { a0[i] = 0.f; a1[i] = 0.f; }
        #pragma unroll
        for (int i = 0; i < 4; ++i) {
            int kl = (i * 2 + ph) * 2;
            float v0 = (kl     < Kr) ? Wg[(size_t)kl * 128 + n]       : 0.f;
            float v1 = (kl + 1 < Kr) ? Wg[(size_t)(kl + 1) * 128 + n] : 0.f;
            unsigned pk = ((unsigned)f2bf(v1) << 16) | (unsigned)f2bf(v0);
            *(unsigned*)&Wt[0][n * WTS + kl] = pk;
        }
        __syncthreads();
        const u16* ap = Asrc + (m0 + lr) * astr + lg * 8;
        for (int ks = 0; ks < nsteps; ++ks) {
            const int cur = ks & 1;
            float v0[4], v1[4];
            const int kb = (ks + 1) * 16;
            if (ks + 1 < nsteps) {
                #pragma unroll
                for (int i = 0; i < 4; ++i) {
                    int kg = kb + (i * 2 + ph) * 2;
                    v0[i] = (kg     < Kr) ? Wg[(size_t)kg * 128 + n]       : 0.f;
                    v1[i] = (kg + 1 < Kr) ? Wg[(size_t)(kg + 1) * 128 + n] : 0.f;
                }
            }
            bf16x8 af = *(const bf16x8*)(ap + ks * 16);
            bf16x8 bf0 = *(const bf16x8*)(&Wt[cur][(n0      + lr) * WTS + lg * 8]);
            bf16x8 bf1 = *(const bf16x8*)(&Wt[cur][(n0 + 32 + lr) * WTS + lg * 8]);
            a0 = __builtin_amdgcn_mfma_f32_32x32x16_bf16(af, bf0, a0, 0, 0, 0);
            a1 = __builtin_amdgcn_mfma_f32_32x32x16_bf16(af, bf1, a1, 0, 0, 0);
            if (ks + 1 < nsteps) {
                #pragma unroll
                for (int i = 0; i < 4; ++i) {
                    int kl = (i * 2 + ph) * 2;
                    unsigned pk = ((unsigned)f2bf(v1[i]) << 16) | (unsigned)f2bf(v0[i]);
                    *(unsigned*)&Wt[cur ^ 1][n * WTS + kl] = pk;
                }
            }
            __syncthreads();
        }
    };

    run_layer(A, KP1, W1, 161, 11, acc0, acc1);
    {   const float bv0 = b1[n0 + lr], bv1 = b1[n0 + 32 + lr];
        #pragma unroll
        for (int r = 0; r < 16; ++r) {
            const int row = (r & 3) + 8 * (r >> 2) + 4 * lg;
            Hb[(m0 + row) * KH + n0 + lr]      = f2bf(fsilu(acc0[r] + bv0));
            Hb[(m0 + row) * KH + n0 + 32 + lr] = f2bf(fsilu(acc1[r] + bv1));
        }
    }
    __syncthreads();

    run_layer(Hb, KH, W2, 128, 8, acc0, acc1);
    __syncthreads();
    {   const float bv0 = b2[n0 + lr], bv1 = b2[n0 + 32 + lr];
        #pragma unroll
        for (int r = 0; r < 16; ++r) {
            const int row = (r & 3) + 8 * (r >> 2) + 4 * lg;
            Hb[(m0 + row) * KH + n0 + lr]      = f2bf(fsilu(acc0[r] + bv0));
            Hb[(m0 + row) * KH + n0 + 32 + lr] = f2bf(fsilu(acc1[r] + bv1));
        }
    }
    __syncthreads();

    run_layer(Hb, KH, W3, 128, 8, acc0, acc1);
    __syncthreads();
    {   const float bv0 = b3[n0 + lr], bv1 = b3[n0 + 32 + lr];
        #pragma unroll
        for (int r = 0; r < 16; ++r) {
            const int row = (r & 3) + 8 * (r >> 2) + 4 * lg;
            Hb[(m0 + row) * KH + n0 + lr]      = f2bf(acc0[r] + bv0);
            Hb[(m0 + row) * KH + n0 + 32 + lr] = f2bf(acc1[r] + bv1);
        }
    }
    __syncthreads();

    if (!MSG) {
        // coalesced copy Hb (mix) -> outws [eg][128]
        #pragma unroll
        for (int p = 0; p < 4; ++p) {
            const int idx = p * 2048 + t * 8;
            const int e   = idx >> 7;
            const int col = idx & 127;
            u16x8 v = *(u16x8*)&Hb[e * KH + col];
            *(u16x8*)&outws[(size_t)(ebase + e) * 128 + col] = v;
        }
    } else {
        // ---------- message epilogue: 4 threads/edge ----------
        // thread r covers: m0 cols [8r,8r+8) and k-groups k=24r..24r+23 (cols 32+3k+d)
        const int me = t >> 2, r = t & 3;
        const u16* Ar = A  + me * KP1;
        const u16* Vr = VS + me * KV;
        const u16* Hr = Hb + me * KH;
        u16* mrow = outws + (size_t)(ebase + me) * 320;
        const float evx = evl[0][me], evy = evl[1][me], evz = evl[2][me];

        {   // m0 block: cols 8r..8r+7
            u16x8 ob;
            #pragma unroll
            for (int j = 0; j < 8; ++j) {
                const int c = 8 * r + j;
                const float vx = bf2f(Vr[3 * c]), vy = bf2f(Vr[3 * c + 1]), vz = bf2f(Vr[3 * c + 2]);
                const float g = bf2f(Hr[c]);
                ob[j] = f2bf((vx * evx + vy * evy + vz * evz) * INV_SQ3 * g);
            }
            *(u16x8*)(mrow + 8 * r) = ob;
        }
        // m1 region: 24 k-groups, 72 outputs, in 3 chunks of 8 groups (24 u16)
        #pragma unroll
        for (int gg = 0; gg < 3; ++gg) {
            u16 ob[24];
            #pragma unroll
            for (int g8 = 0; g8 < 8; ++g8) {
                const int k = 24 * r + gg * 8 + g8;
                const float gate = bf2f(Hr[32 + k]);
                if (k < 64) {
                    const float s = bf2f(Ar[k]) * gate;
                    ob[3 * g8 + 0] = f2bf(s * evx);
                    ob[3 * g8 + 1] = f2bf(s * evy);
                    ob[3 * g8 + 2] = f2bf(s * evz);
                } else {
                    const int c = k - 64;
                    const float vx = bf2f(Vr[3 * c]), vy = bf2f(Vr[3 * c + 1]), vz = bf2f(Vr[3 * c + 2]);
                    const float sc = INV_SQ2 * gate;
                    ob[3 * g8 + 0] = f2bf((vy * evz - vz * evy) * sc);
                    ob[3 * g8 + 1] = f2bf((vz * evx - vx * evz) * sc);
                    ob[3 * g8 + 2] = f2bf((vx * evy - vy * evx) * sc);
                }
            }
            u16* dst = mrow + 32 + 72 * r + 24 * gg;
            u16x8 p0, p1, p2;
            #pragma unroll
            for (int q = 0; q < 8; ++q) { p0[q] = ob[q]; p1[q] = ob[8 + q]; p2[q] = ob[16 + q]; }
            *(u16x8*)(dst)      = p0;
            *(u16x8*)(dst + 8)  = p1;
            *(u16x8*)(dst + 16) = p2;
        }
    }
}

// ==================== phase 2 (v2): coalesced row-sum gather ====================

__global__ __launch_bounds__(256)
void msg_gather_kernel(const int* __restrict__ rowp,
                       const int* __restrict__ elist,
                       const u16* __restrict__ msg,
                       float* __restrict__ out)
{
    const int gw = (blockIdx.x * 256 + threadIdx.x) >> 6;   // node
    const int l  = threadIdx.x & 63;
    if (gw >= N_NODES || l >= 40) return;

    const int rp0 = rowp[gw], rp1 = rowp[gw + 1];
    float acc[8] = {0.f, 0.f, 0.f, 0.f, 0.f, 0.f, 0.f, 0.f};
    const u16* mbase = msg + (size_t)l * 8;

    int j = rp0;
    for (; j + 1 < rp1; j += 2) {
        const int e0 = elist[j], e1 = elist[j + 1];
        const u16x8 v0 = *(const u16x8*)(mbase + (size_t)e0 * 320);
        const u16x8 v1 = *(const u16x8*)(mbase + (size_t)e1 * 320);
        #pragma unroll
        for (int q = 0; q < 8; ++q) acc[q] += bf2f(v0[q]) + bf2f(v1[q]);
    }
    if (j < rp1) {
        const int e0 = elist[j];
        const u16x8 v0 = *(const u16x8*)(mbase + (size_t)e0 * 320);
        #pragma unroll
        for (int q = 0; q < 8; ++q) acc[q] += bf2f(v0[q]);
    }

    float* orow = out + (size_t)gw * OUTC + l * 8;
    *(float4*)(orow)     = make_float4(acc[0] * INV_AVG, acc[1] * INV_AVG,
                                       acc[2] * INV_AVG, acc[3] * INV_AVG);
    *(float4*)(orow + 4) = make_float4(acc[4] * INV_AVG, acc[5] * INV_AVG,
                                       acc[6] * INV_AVG, acc[7] * INV_AVG);
}

// ==================== phase 2 (v1 fallback): round-3 gather ====================

__global__ __launch_bounds__(256)
void node_gather_kernel(const float* __restrict__ node_scalars,
                        const float* __restrict__ node_vectors,
                        const float* __restrict__ edge_vec,
                        const int* __restrict__ senders,
                        const int* __restrict__ rowp,
                        const int* __restrict__ elist,
                        const u16* __restrict__ mixws,
                        float* __restrict__ out)
{
    const int gw = (blockIdx.x * 256 + threadIdx.x) >> 6;
    const int l  = threadIdx.x & 63;
    if (gw >= N_NODES) return;

    const int rp0 = rowp[gw], rp1 = rowp[gw + 1];

    int mode[5], kk[5], dd[5], gi[5];
    #pragma unroll
    for (int cc = 0; cc < 5; ++cc) {
        const int col = 5 * l + cc;
        if (col < 32) { mode[cc] = 0; kk[cc] = col; dd[cc] = 0; gi[cc] = col; }
        else {
            const int idx = col - 32;
            const int k = idx / 3;
            const int d = idx - 3 * k;
            gi[cc] = 32 + k;
            if (k < 64) { mode[cc] = 1; kk[cc] = k;      dd[cc] = d; }
            else        { mode[cc] = 2; kk[cc] = k - 64; dd[cc] = d; }
        }
    }

    float acc[5] = {0.f, 0.f, 0.f, 0.f, 0.f};

    for (int j = rp0; j < rp1; ++j) {
        const int e = elist[j];
        const int s = senders[e];
        const float evx = edge_vec[(size_t)e * 3 + 0];
        const float evy = edge_vec[(size_t)e * 3 + 1];
        const float evz = edge_vec[(size_t)e * 3 + 2];
        const float* ns = node_scalars + (size_t)s * 64;
        const float* nv = node_vectors + (size_t)s * 96;
        const u16*   mg = mixws + (size_t)e * 128;
        #pragma unroll
        for (int cc = 0; cc < 5; ++cc) {
            const float g = bf2f(mg[gi[cc]]);
            float f;
            if (mode[cc] == 0) {
                const int c = kk[cc];
                f = (nv[3 * c] * evx + nv[3 * c + 1] * evy + nv[3 * c + 2] * evz) * INV_SQ3;
            } else if (mode[cc] == 1) {
                const float evd = (dd[cc] == 0) ? evx : ((dd[cc] == 1) ? evy : evz);
                f = ns[kk[cc]] * evd;
            } else {
                const int c = kk[cc];
                const float vx = nv[3 * c], vy = nv[3 * c + 1], vz = nv[3 * c + 2];
                float cr;
                if (dd[cc] == 0)      cr = vy * evz - vz * evy;
                else if (dd[cc] == 1) cr = vz * evx - vx * evz;
                else                  cr = vx * evy - vy * evx;
                f = cr * INV_SQ2;
            }
            acc[cc] = fmaf(f, g, acc[cc]);
        }
    }

    float* orow = out + (size_t)gw * OUTC + 5 * l;
    #pragma unroll
    for (int cc = 0; cc < 5; ++cc) orow[cc] = acc[cc] * INV_AVG;
}

// ==================== last-resort fallback: atomic fused ====================

__global__ __launch_bounds__(256, 2)
void fused_mpconv_atomic(const float* __restrict__ node_scalars,
                         const float* __restrict__ node_vectors,
                         const float* __restrict__ edge_vec,
                         const float* __restrict__ sef,
                         const float* __restrict__ lengths,
                         const int* __restrict__ senders,
                         const int* __restrict__ receivers,
                         const float* __restrict__ W1, const float* __restrict__ b1,
                         const float* __restrict__ W2, const float* __restrict__ b2,
                         const float* __restrict__ W3, const float* __restrict__ b3,
                         float* __restrict__ out)
{
    __shared__ u16 A [EB * KP1];
    __shared__ u16 VS[EB * KV];
    __shared__ u16 Hb[EB * KH];
    __shared__ u16 Wt[2][128 * WTS];
    __shared__ float evl[3][EB];
    __shared__ int sidx[EB], ridx[EB];

    const int t = threadIdx.x;
    const int ebase = blockIdx.x * EB;

    {   const int e = t & 63, sub = t >> 6;
        const int eg = ebase + e; const bool ve = eg < N_EDGES;
        if (sub == 0)      sidx[e] = ve ? senders[eg] : 0;
        else if (sub == 1) ridx[e] = ve ? receivers[eg] : 0;
        else if (sub == 2) {
            evl[0][e] = ve ? edge_vec[(size_t)eg * 3 + 0] : 0.f;
            evl[1][e] = ve ? edge_vec[(size_t)eg * 3 + 1] : 0.f;
            evl[2][e] = ve ? edge_vec[(size_t)eg * 3 + 2] : 0.f;
        }
    }
    __syncthreads();

    {   const int me = t >> 2, q = t & 3;
        const int eg = ebase + me; const bool ve = eg < N_EDGES;
        const int si = sidx[me], ri = ridx[me];
        u16* Ar = A + me * KP1;
        stage16(node_scalars + (size_t)si * 64 + q * 16, Ar + q * 16,       ve);
        stage16(node_scalars + (size_t)ri * 64 + q * 16, Ar + 64 + q * 16,  ve);
        stage8 (sef          + (size_t)eg * 32 + q * 8,  Ar + 128 + q * 8,  ve);
        u16x8 zz = (u16x8)0;
        *(u16x8*)(Ar + 160 + q * 8) = zz;
        if (q == 0) *(u16x8*)(Ar + 192) = zz;
        stage16(node_vectors + (size_t)si * 96 + q * 24,      VS + me * KV + q * 24,      ve);
        stage8 (node_vectors + (size_t)si * 96 + q * 24 + 16, VS + me * KV + q * 24 + 16, ve);
        if (q == 0) Ar[160] = f2bf(ve ? lengths[eg] : 0.f);
    }
    __syncthreads();

    const int w  = t >> 6, l = t & 63;
    const int lr = l & 31;
    const int lg = l >> 5;
    const int m0 = (w >> 1) * 32;
    const int n0 = (w & 1) * 64;

    f32x16 acc0, acc1;
    const int n  = t & 127, ph = t >> 7;

    auto run_layer = [&](const u16* Asrc, int astr, const float* Wg, int Kr, int nsteps,
                         f32x16& a0, f32x16& a1) {
        #pragma unroll
        for (int i = 0; i < 16; ++i) { a0[i] = 0.f; a1[i] = 0.f; }
        #pragma unroll
        for (int i = 0; i < 4; ++i) {
            int kl = (i * 2 + ph) * 2;
            float v0 = (kl     < Kr) ? Wg[(size_t)kl * 128 + n]       : 0.f;
            float v1 = (kl + 1 < Kr) ? Wg[(size_t)(kl + 1) * 128 + n] : 0.f;
            unsigned pk = ((unsigned)f2bf(v1) << 16) | (unsigned)f2bf(v0);
            *(unsigned*)&Wt[0][n * WTS + kl] = pk;
        }
        __syncthreads();
        const u16* ap = Asrc + (m0 + lr) * astr + lg * 8;
        for (int ks = 0; ks < nsteps; ++ks) {
            const int cur = ks & 1;
            float v0[4], v1[4];
            const int kb = (ks + 1) * 16;
            if (ks + 1 < nsteps) {
                #pragma unroll
                for (int i = 0; i < 4; ++i) {
                    int kg = kb + (i * 2 + ph) * 2;
                    v0[i] = (kg     < Kr) ? Wg[(size_t)kg * 128 + n]       : 0.f;
                    v1[i] = (kg + 1 < Kr) ? Wg[(size_t)(kg + 1) * 128 + n] : 0.f;
                }
            }
            bf16x8 af = *(const bf16x8*)(ap + ks * 16);
            bf16x8 bf0 = *(const bf16x8*)(&Wt[cur][(n0      + lr) * WTS + lg * 8]);
            bf16x8 bf1 = *(const bf16x8*)(&Wt[cur][(n0 + 32 + lr) * WTS + lg * 8]);
            a0 = __builtin_amdgcn_mfma_f32_32x32x16_bf16(af, bf0, a0, 0, 0, 0);
            a1 = __builtin_amdgcn_mfma_f32_32x32x16_bf16(af, bf1, a1, 0, 0, 0);
            if (ks + 1 < nsteps) {
                #pragma unroll
                for (int i = 0; i < 4; ++i) {
                    int kl = (i * 2 + ph) * 2;
                    unsigned pk = ((unsigned)f2bf(v1[i]) << 16) | (unsigned)f2bf(v0[i]);
                    *(unsigned*)&Wt[cur ^ 1][n * WTS + kl] = pk;
                }
            }
            __syncthreads();
        }
    };

    run_layer(A, KP1, W1, 161, 11, acc0, acc1);
    {   const float bv0 = b1[n0 + lr], bv1 = b1[n0 + 32 + lr];
        #pragma unroll
        for (int r = 0; r < 16; ++r) {
            const int row = (r & 3) + 8 * (r >> 2) + 4 * lg;
            Hb[(m0 + row) * KH + n0 + lr]      = f2bf(fsilu(acc0[r] + bv0));
            Hb[(m0 + row) * KH + n0 + 32 + lr] = f2bf(fsilu(acc1[r] + bv1));
        }
    }
    __syncthreads();

    run_layer(Hb, KH, W2, 128, 8, acc0, acc1);
    __syncthreads();
    {   const float bv0 = b2[n0 + lr], bv1 = b2[n0 + 32 + lr];
        #pragma unroll
        for (int r = 0; r < 16; ++r) {
            const int row = (r & 3) + 8 * (r >> 2) + 4 * lg;
            Hb[(m0 + row) * KH + n0 + lr]      = f2bf(fsilu(acc0[r] + bv0));
            Hb[(m0 + row) * KH + n0 + 32 + lr] = f2bf(fsilu(acc1[r] + bv1));
        }
    }
    __syncthreads();

    run_layer(Hb, KH, W3, 128, 8, acc0, acc1);
    __syncthreads();
    {   const float bv0 = b3[n0 + lr], bv1 = b3[n0 + 32 + lr];
        #pragma unroll
        for (int r = 0; r < 16; ++r) {
            const int row = (r & 3) + 8 * (r >> 2) + 4 * lg;
            Hb[(m0 + row) * KH + n0 + lr]      = f2bf(acc0[r] + bv0);
            Hb[(m0 + row) * KH + n0 + 32 + lr] = f2bf(acc1[r] + bv1);
        }
    }
    __syncthreads();

    {   const int me = t >> 2, r = t & 3;
        const int eg2 = ebase + me;
        if (eg2 < N_EDGES) {
            const int row = ridx[me];
            const float evx = evl[0][me], evy = evl[1][me], evz = evl[2][me];
            float* orow = out + (size_t)row * OUTC;
            const u16* Ar = A  + me * KP1;
            const u16* Vr = VS + me * KV;
            const u16* Hr = Hb + me * KH;
            for (int col = r; col < OUTC; col += 4) {
                float val;
                if (col < 32) {
                    const int c = col;
                    const float vx = bf2f(Vr[3 * c]), vy = bf2f(Vr[3 * c + 1]), vz = bf2f(Vr[3 * c + 2]);
                    val = (vx * evx + vy * evy + vz * evz) * INV_SQ3 * bf2f(Hr[c]);
                } else {
                    const int idx = col - 32;
                    const int k = idx / 3;
                    const int d = idx - 3 * k;
                    const float g = bf2f(Hr[32 + k]);
                    if (k < 64) {
                        const float evd = (d == 0) ? evx : ((d == 1) ? evy : evz);
                        val = bf2f(Ar[k]) * evd * g;
                    } else {
                        const int c = k - 64;
                        const float vx = bf2f(Vr[3 * c]), vy = bf2f(Vr[3 * c + 1]), vz = bf2f(Vr[3 * c + 2]);
                        float cr;
                        if (d == 0)      cr = vy * evz - vz * evy;
                        else if (d == 1) cr = vz * evx - vx * evz;
                        else             cr = vx * evy - vy * evx;
                        val = cr * INV_SQ2 * g;
                    }
                }
                atomicAdd(&orow[col], val * INV_AVG);
            }
        }
    }
}

// ==================== launch ====================

extern "C" void kernel_launch(void* const* d_in, const int* in_sizes, int n_in,
                              void* d_out, int out_size, void* d_ws, size_t ws_size,
                              hipStream_t stream) {
    (void)in_sizes; (void)n_in;
    const float* node_scalars = (const float*)d_in[0];
    const float* node_vectors = (const float*)d_in[1];
    const float* edge_vec     = (const float*)d_in[2];
    const float* sef          = (const float*)d_in[3];
    const float* lengths      = (const float*)d_in[4];
    const int*   senders      = (const int*)d_in[5];
    const int*   receivers    = (const int*)d_in[6];
    const float* W1 = (const float*)d_in[7];
    const float* b1 = (const float*)d_in[8];
    const float* W2 = (const float*)d_in[9];
    const float* b2 = (const float*)d_in[10];
    const float* W3 = (const float*)d_in[11];
    const float* b3 = (const float*)d_in[12];
    float* out = (float*)d_out;

    auto align256 = [](size_t x) { return (x + 255) & ~(size_t)255; };

    // v2 layout: msg[E][320] bf16 + CSR
    size_t off2 = 0;
    const size_t o2_msg     = off2; off2 += align256((size_t)MIXROWS * 320 * sizeof(u16));
    const size_t o2_counts  = off2; off2 += align256((size_t)N_NODES * sizeof(int));
    const size_t o2_rowp    = off2; off2 += align256((size_t)(N_NODES + 1) * sizeof(int));
    const size_t o2_cursors = off2; off2 += align256((size_t)(N_NODES + 1) * sizeof(int));
    const size_t o2_part    = off2; off2 += align256(64 * sizeof(int));
    const size_t o2_elist   = off2; off2 += align256((size_t)N_EDGES * sizeof(int));
    const size_t ws_v2 = off2;

    // v1 layout: mix[E][128] bf16 + CSR
    size_t off1 = 0;
    const size_t o1_mix     = off1; off1 += align256((size_t)MIXROWS * 128 * sizeof(u16));
    const size_t o1_counts  = off1; off1 += align256((size_t)N_NODES * sizeof(int));
    const size_t o1_rowp    = off1; off1 += align256((size_t)(N_NODES + 1) * sizeof(int));
    const size_t o1_cursors = off1; off1 += align256((size_t)(N_NODES + 1) * sizeof(int));
    const size_t o1_part    = off1; off1 += align256(64 * sizeof(int));
    const size_t o1_elist   = off1; off1 += align256((size_t)N_EDGES * sizeof(int));
    const size_t ws_v1 = off1;

    const int nblk_e = (N_EDGES + EB - 1) / EB;
    char* ws = (char*)d_ws;

    if (ws_size >= ws_v2) {
        u16* msg     = (u16*)(ws + o2_msg);
        int* counts  = (int*)(ws + o2_counts);
        int* rowp    = (int*)(ws + o2_rowp);
        int* cursors = (int*)(ws + o2_cursors);
        int* part    = (int*)(ws + o2_part);
        int* elist   = (int*)(ws + o2_elist);

        hipMemsetAsync(counts, 0, (size_t)N_NODES * sizeof(int), stream);
        hist_kernel<<<(N_EDGES + 255) / 256, 256, 0, stream>>>(receivers, counts);
        scan_k1<<<NBLK1, 256, 0, stream>>>(counts, rowp, part);
        scan_k2<<<1, 64, 0, stream>>>(part);
        scan_k3<<<NBLK1, 256, 0, stream>>>(rowp, part, cursors);
        fill_kernel<<<(N_EDGES + 255) / 256, 256, 0, stream>>>(receivers, cursors, elist);

        mlp_phase_kernel<true><<<nblk_e, 256, 0, stream>>>(
            node_scalars, node_vectors, edge_vec, sef, lengths, senders, receivers,
            W1, b1, W2, b2, W3, b3, msg);

        msg_gather_kernel<<<(N_NODES * 64 + 255) / 256, 256, 0, stream>>>(
            rowp, elist, msg, out);
    } else if (ws_size >= ws_v1) {
        u16* mixws   = (u16*)(ws + o1_mix);
        int* counts  = (int*)(ws + o1_counts);
        int* rowp    = (int*)(ws + o1_rowp);
        int* cursors = (int*)(ws + o1_cursors);
        int* part    = (int*)(ws + o1_part);
        int* elist   = (int*)(ws + o1_elist);

        hipMemsetAsync(counts, 0, (size_t)N_NODES * sizeof(int), stream);
        hist_kernel<<<(N_EDGES + 255) / 256, 256, 0, stream>>>(receivers, counts);
        scan_k1<<<NBLK1, 256, 0, stream>>>(counts, rowp, part);
        scan_k2<<<1, 64, 0, stream>>>(part);
        scan_k3<<<NBLK1, 256, 0, stream>>>(rowp, part, cursors);
        fill_kernel<<<(N_EDGES + 255) / 256, 256, 0, stream>>>(receivers, cursors, elist);

        mlp_phase_kernel<false><<<nblk_e, 256, 0, stream>>>(
            node_scalars, node_vectors, edge_vec, sef, lengths, senders, receivers,
            W1, b1, W2, b2, W3, b3, mixws);

        node_gather_kernel<<<(N_NODES * 64 + 255) / 256, 256, 0, stream>>>(
            node_scalars, node_vectors, edge_vec, senders,
            rowp, elist, mixws, out);
    } else {
        hipMemsetAsync(out, 0, (size_t)out_size * sizeof(float), stream);
        fused_mpconv_atomic<<<nblk_e, 256, 0, stream>>>(
            node_scalars, node_vectors, edge_vec, sef, lengths,
            senders, receivers, W1, b1, W2, b2, W3, b3, out);
    }
}

// Round 5
// 715.047 us; speedup vs baseline: 1.3173x; 1.3173x over previous
//
#include <hip/hip_runtime.h>

#define N_NODES 50000
#define N_EDGES 500000
#define EB 64
#define KP1 200          // A row stride (bf16 elems)
#define KH  136          // H row stride
#define KV  104          // VS row stride
#define WTS 40           // Wt row stride
#define OUTC 320
#define NBLK1 49         // ceil(50000/1024) scan level-1 blocks
#define INV_SQ3 0.57735026918962576f
#define INV_SQ2 0.70710678118654752f
#define INV_AVG 0.1f

typedef short bf16x8 __attribute__((ext_vector_type(8)));
typedef unsigned short u16;
typedef u16 u16x8 __attribute__((ext_vector_type(8)));
typedef float f32x16 __attribute__((ext_vector_type(16)));

__device__ __forceinline__ float bf2f(u16 h) {
    union { unsigned u; float f; } x; x.u = ((unsigned)h) << 16; return x.f;
}
__device__ __forceinline__ u16 f2bf(float f) {   // RNE
    unsigned u = __builtin_bit_cast(unsigned, f);
    u += 0x7FFFu + ((u >> 16) & 1u);
    return (u16)(u >> 16);
}
__device__ __forceinline__ float fsilu(float x) {
    return x * __builtin_amdgcn_rcpf(1.f + __expf(-x));
}

__device__ __forceinline__ void stage16(const float* g, u16* l, bool v) {
    float4 a0, a1, a2, a3;
    const float4 z = make_float4(0.f, 0.f, 0.f, 0.f);
    if (v) { a0 = *(const float4*)(g);     a1 = *(const float4*)(g + 4);
             a2 = *(const float4*)(g + 8); a3 = *(const float4*)(g + 12); }
    else   { a0 = z; a1 = z; a2 = z; a3 = z; }
    u16x8 p0 = { f2bf(a0.x), f2bf(a0.y), f2bf(a0.z), f2bf(a0.w),
                 f2bf(a1.x), f2bf(a1.y), f2bf(a1.z), f2bf(a1.w) };
    u16x8 p1 = { f2bf(a2.x), f2bf(a2.y), f2bf(a2.z), f2bf(a2.w),
                 f2bf(a3.x), f2bf(a3.y), f2bf(a3.z), f2bf(a3.w) };
    *(u16x8*)(l) = p0; *(u16x8*)(l + 8) = p1;
}
__device__ __forceinline__ void stage8(const float* g, u16* l, bool v) {
    float4 a0, a1;
    const float4 z = make_float4(0.f, 0.f, 0.f, 0.f);
    if (v) { a0 = *(const float4*)(g); a1 = *(const float4*)(g + 4); }
    else   { a0 = z; a1 = z; }
    u16x8 p0 = { f2bf(a0.x), f2bf(a0.y), f2bf(a0.z), f2bf(a0.w),
                 f2bf(a1.x), f2bf(a1.y), f2bf(a1.z), f2bf(a1.w) };
    *(u16x8*)(l) = p0;
}

// ==================== CSR build ====================

__global__ void hist_kernel(const int* __restrict__ recv, int* __restrict__ counts) {
    const int e = blockIdx.x * 256 + threadIdx.x;
    if (e < N_EDGES) atomicAdd(&counts[recv[e]], 1);
}

__global__ __launch_bounds__(256) void scan_k1(const int* __restrict__ counts,
                                               int* __restrict__ rowp,
                                               int* __restrict__ partials) {
    __shared__ int sd[256];
    const int t = threadIdx.x;
    const int base = blockIdx.x * 1024 + t * 4;
    int c0 = 0, c1 = 0, c2 = 0, c3 = 0;
    if (base + 3 < N_NODES) {
        int4 v = *(const int4*)&counts[base];
        c0 = v.x; c1 = v.y; c2 = v.z; c3 = v.w;
    } else {
        if (base     < N_NODES) c0 = counts[base];
        if (base + 1 < N_NODES) c1 = counts[base + 1];
        if (base + 2 < N_NODES) c2 = counts[base + 2];
        if (base + 3 < N_NODES) c3 = counts[base + 3];
    }
    const int T = c0 + c1 + c2 + c3;
    sd[t] = T; __syncthreads();
    for (int off = 1; off < 256; off <<= 1) {
        int v = (t >= off) ? sd[t - off] : 0;
        __syncthreads();
        sd[t] += v;
        __syncthreads();
    }
    const int excl = sd[t] - T;
    if (base     < N_NODES) rowp[base]     = excl;
    if (base + 1 < N_NODES) rowp[base + 1] = excl + c0;
    if (base + 2 < N_NODES) rowp[base + 2] = excl + c0 + c1;
    if (base + 3 < N_NODES) rowp[base + 3] = excl + c0 + c1 + c2;
    if (t == 255) partials[blockIdx.x] = sd[255];
}

__global__ __launch_bounds__(64) void scan_k2(int* __restrict__ partials) {
    __shared__ int sd[64];
    const int t = threadIdx.x;
    const int v0 = (t < NBLK1) ? partials[t] : 0;
    sd[t] = v0; __syncthreads();
    for (int off = 1; off < 64; off <<= 1) {
        int v = (t >= off) ? sd[t - off] : 0;
        __syncthreads();
        sd[t] += v;
        __syncthreads();
    }
    if (t < NBLK1) partials[t] = sd[t] - v0;
}

__global__ __launch_bounds__(256) void scan_k3(int* __restrict__ rowp,
                                               const int* __restrict__ partials,
                                               int* __restrict__ cursors) {
    const int add = partials[blockIdx.x];
    const int base = blockIdx.x * 1024 + threadIdx.x * 4;
    #pragma unroll
    for (int i = 0; i < 4; ++i) {
        const int idx = base + i;
        if (idx < N_NODES) {
            const int v = rowp[idx] + add;
            rowp[idx] = v;
            cursors[idx] = v;
        }
    }
    if (blockIdx.x == 0 && threadIdx.x == 0) rowp[N_NODES] = N_EDGES;
}

__global__ void fill_kernel(const int* __restrict__ recv,
                            int* __restrict__ cursors, int* __restrict__ elist) {
    const int e = blockIdx.x * 256 + threadIdx.x;
    if (e < N_EDGES) {
        const int r = recv[e];
        const int pos = atomicAdd(&cursors[r], 1);
        elist[pos] = e;
    }
}

// ==================== phase E: fused MLP + message epilogue (chunked) ====================
// processes edges [elo, elo+ecnt); writes msg[local_edge][320] bf16

__global__ __launch_bounds__(256, 2)
void mlp_msg_kernel(const float* __restrict__ node_scalars,
                    const float* __restrict__ node_vectors,
                    const float* __restrict__ edge_vec,
                    const float* __restrict__ sef,
                    const float* __restrict__ lengths,
                    const int* __restrict__ senders,
                    const int* __restrict__ receivers,
                    const float* __restrict__ W1, const float* __restrict__ b1,
                    const float* __restrict__ W2, const float* __restrict__ b2,
                    const float* __restrict__ W3, const float* __restrict__ b3,
                    u16* __restrict__ msg, int elo, int ecnt)
{
    __shared__ u16 A [EB * KP1];
    __shared__ u16 VS[EB * KV];
    __shared__ u16 Hb[EB * KH];
    __shared__ u16 Wt[2][128 * WTS];
    __shared__ float evl[3][EB];
    __shared__ int sidx[EB];

    const int t = threadIdx.x;
    const int lbase = blockIdx.x * EB;          // local edge base (msg row base)
    const int ebase = elo + lbase;              // global edge base

    {   const int e = t & 63, sub = t >> 6;
        const int eg = ebase + e; const bool ve = (lbase + e) < ecnt;
        if (sub == 0)      sidx[e] = ve ? senders[eg] : 0;
        else if (sub == 2) {
            evl[0][e] = ve ? edge_vec[(size_t)eg * 3 + 0] : 0.f;
            evl[1][e] = ve ? edge_vec[(size_t)eg * 3 + 1] : 0.f;
            evl[2][e] = ve ? edge_vec[(size_t)eg * 3 + 2] : 0.f;
        }
    }
    __syncthreads();

    {   const int me = t >> 2, q = t & 3;
        const int eg = ebase + me; const bool ve = (lbase + me) < ecnt;
        const int si = sidx[me];
        const int ri = ve ? receivers[eg] : 0;
        u16* Ar = A + me * KP1;
        stage16(node_scalars + (size_t)si * 64 + q * 16, Ar + q * 16,       ve);
        stage16(node_scalars + (size_t)ri * 64 + q * 16, Ar + 64 + q * 16,  ve);
        stage8 (sef          + (size_t)eg * 32 + q * 8,  Ar + 128 + q * 8,  ve);
        u16x8 zz = (u16x8)0;
        *(u16x8*)(Ar + 160 + q * 8) = zz;
        if (q == 0) *(u16x8*)(Ar + 192) = zz;
        stage16(node_vectors + (size_t)si * 96 + q * 24,      VS + me * KV + q * 24,      ve);
        stage8 (node_vectors + (size_t)si * 96 + q * 24 + 16, VS + me * KV + q * 24 + 16, ve);
        if (q == 0) Ar[160] = f2bf(ve ? lengths[eg] : 0.f);
    }
    __syncthreads();

    const int w  = t >> 6, l = t & 63;
    const int lr = l & 31;
    const int lg = l >> 5;
    const int m0 = (w >> 1) * 32;
    const int n0 = (w & 1) * 64;

    f32x16 acc0, acc1;
    const int n  = t & 127, ph = t >> 7;

    auto run_layer = [&](const u16* Asrc, int astr, const float* Wg, int Kr, int nsteps,
                         f32x16& a0, f32x16& a1) {
        #pragma unroll
        for (int i = 0; i < 16; ++i) { a0[i] = 0.f; a1[i] = 0.f; }
        #pragma unroll
        for (int i = 0; i < 4; ++i) {
            int kl = (i * 2 + ph) * 2;
            float v0 = (kl     < Kr) ? Wg[(size_t)kl * 128 + n]       : 0.f;
            float v1 = (kl + 1 < Kr) ? Wg[(size_t)(kl + 1) * 128 + n] : 0.f;
            unsigned pk = ((unsigned)f2bf(v1) << 16) | (unsigned)f2bf(v0);
            *(unsigned*)&Wt[0][n * WTS + kl] = pk;
        }
        __syncthreads();
        const u16* ap = Asrc + (m0 + lr) * astr + lg * 8;
        for (int ks = 0; ks < nsteps; ++ks) {
            const int cur = ks & 1;
            float v0[4], v1[4];
            const int kb = (ks + 1) * 16;
            if (ks + 1 < nsteps) {
                #pragma unroll
                for (int i = 0; i < 4; ++i) {
                    int kg = kb + (i * 2 + ph) * 2;
                    v0[i] = (kg     < Kr) ? Wg[(size_t)kg * 128 + n]       : 0.f;
                    v1[i] = (kg + 1 < Kr) ? Wg[(size_t)(kg + 1) * 128 + n] : 0.f;
                }
            }
            bf16x8 af = *(const bf16x8*)(ap + ks * 16);
            bf16x8 bf0 = *(const bf16x8*)(&Wt[cur][(n0      + lr) * WTS + lg * 8]);
            bf16x8 bf1 = *(const bf16x8*)(&Wt[cur][(n0 + 32 + lr) * WTS + lg * 8]);
            a0 = __builtin_amdgcn_mfma_f32_32x32x16_bf16(af, bf0, a0, 0, 0, 0);
            a1 = __builtin_amdgcn_mfma_f32_32x32x16_bf16(af, bf1, a1, 0, 0, 0);
            if (ks + 1 < nsteps) {
                #pragma unroll
                for (int i = 0; i < 4; ++i) {
                    int kl = (i * 2 + ph) * 2;
                    unsigned pk = ((unsigned)f2bf(v1[i]) << 16) | (unsigned)f2bf(v0[i]);
                    *(unsigned*)&Wt[cur ^ 1][n * WTS + kl] = pk;
                }
            }
            __syncthreads();
        }
    };

    run_layer(A, KP1, W1, 161, 11, acc0, acc1);
    {   const float bv0 = b1[n0 + lr], bv1 = b1[n0 + 32 + lr];
        #pragma unroll
        for (int r = 0; r < 16; ++r) {
            const int row = (r & 3) + 8 * (r >> 2) + 4 * lg;
            Hb[(m0 + row) * KH + n0 + lr]      = f2bf(fsilu(acc0[r] + bv0));
            Hb[(m0 + row) * KH + n0 + 32 + lr] = f2bf(fsilu(acc1[r] + bv1));
        }
    }
    __syncthreads();

    run_layer(Hb, KH, W2, 128, 8, acc0, acc1);
    __syncthreads();
    {   const float bv0 = b2[n0 + lr], bv1 = b2[n0 + 32 + lr];
        #pragma unroll
        for (int r = 0; r < 16; ++r) {
            const int row = (r & 3) + 8 * (r >> 2) + 4 * lg;
            Hb[(m0 + row) * KH + n0 + lr]      = f2bf(fsilu(acc0[r] + bv0));
            Hb[(m0 + row) * KH + n0 + 32 + lr] = f2bf(fsilu(acc1[r] + bv1));
        }
    }
    __syncthreads();

    run_layer(Hb, KH, W3, 128, 8, acc0, acc1);
    __syncthreads();
    {   const float bv0 = b3[n0 + lr], bv1 = b3[n0 + 32 + lr];
        #pragma unroll
        for (int r = 0; r < 16; ++r) {
            const int row = (r & 3) + 8 * (r >> 2) + 4 * lg;
            Hb[(m0 + row) * KH + n0 + lr]      = f2bf(acc0[r] + bv0);
            Hb[(m0 + row) * KH + n0 + 32 + lr] = f2bf(acc1[r] + bv1);
        }
    }
    __syncthreads();

    // ---------- message epilogue: 4 threads/edge ----------
    // thread r covers: m0 cols [8r,8r+8) and k-groups k=24r..24r+23 (cols 32+3k+d)
    {
        const int me = t >> 2, r = t & 3;
        const u16* Ar = A  + me * KP1;
        const u16* Vr = VS + me * KV;
        const u16* Hr = Hb + me * KH;
        u16* mrow = msg + (size_t)(lbase + me) * 320;
        const float evx = evl[0][me], evy = evl[1][me], evz = evl[2][me];

        {   // m0 block: cols 8r..8r+7
            u16x8 ob;
            #pragma unroll
            for (int j = 0; j < 8; ++j) {
                const int c = 8 * r + j;
                const float vx = bf2f(Vr[3 * c]), vy = bf2f(Vr[3 * c + 1]), vz = bf2f(Vr[3 * c + 2]);
                const float g = bf2f(Hr[c]);
                ob[j] = f2bf((vx * evx + vy * evy + vz * evz) * INV_SQ3 * g);
            }
            *(u16x8*)(mrow + 8 * r) = ob;
        }
        // m1 region: 24 k-groups, 72 outputs, in 3 chunks of 8 groups (24 u16)
        #pragma unroll
        for (int gg = 0; gg < 3; ++gg) {
            u16 ob[24];
            #pragma unroll
            for (int g8 = 0; g8 < 8; ++g8) {
                const int k = 24 * r + gg * 8 + g8;
                const float gate = bf2f(Hr[32 + k]);
                if (k < 64) {
                    const float s = bf2f(Ar[k]) * gate;
                    ob[3 * g8 + 0] = f2bf(s * evx);
                    ob[3 * g8 + 1] = f2bf(s * evy);
                    ob[3 * g8 + 2] = f2bf(s * evz);
                } else {
                    const int c = k - 64;
                    const float vx = bf2f(Vr[3 * c]), vy = bf2f(Vr[3 * c + 1]), vz = bf2f(Vr[3 * c + 2]);
                    const float sc = INV_SQ2 * gate;
                    ob[3 * g8 + 0] = f2bf((vy * evz - vz * evy) * sc);
                    ob[3 * g8 + 1] = f2bf((vz * evx - vx * evz) * sc);
                    ob[3 * g8 + 2] = f2bf((vx * evy - vy * evx) * sc);
                }
            }
            u16* dst = mrow + 32 + 72 * r + 24 * gg;
            u16x8 p0, p1, p2;
            #pragma unroll
            for (int q = 0; q < 8; ++q) { p0[q] = ob[q]; p1[q] = ob[8 + q]; p2[q] = ob[16 + q]; }
            *(u16x8*)(dst)      = p0;
            *(u16x8*)(dst + 8)  = p1;
            *(u16x8*)(dst + 16) = p2;
        }
    }
}

// ==================== phase 2: chunked coalesced row-sum gather ====================

__global__ __launch_bounds__(256)
void msg_gather_chunk(const int* __restrict__ rowp,
                      const int* __restrict__ elist,
                      const u16* __restrict__ msg,
                      float* __restrict__ out,
                      int elo, int ehi, int first)
{
    const int gw = (blockIdx.x * 256 + threadIdx.x) >> 6;   // node
    const int l  = threadIdx.x & 63;
    if (gw >= N_NODES || l >= 40) return;

    const int rp0 = rowp[gw], rp1 = rowp[gw + 1];
    float racc[8] = {0.f, 0.f, 0.f, 0.f, 0.f, 0.f, 0.f, 0.f};
    const u16* mbase = msg + (size_t)l * 8;

    bool any = false;
    for (int j = rp0; j < rp1; ++j) {
        const int e = elist[j];
        if (e < elo || e >= ehi) continue;
        const u16x8 v = *(const u16x8*)(mbase + (size_t)(e - elo) * 320);
        #pragma unroll
        for (int q = 0; q < 8; ++q) racc[q] += bf2f(v[q]);
        any = true;
    }

    float* orow = out + (size_t)gw * OUTC + l * 8;
    if (first) {
        *(float4*)(orow)     = make_float4(racc[0] * INV_AVG, racc[1] * INV_AVG,
                                           racc[2] * INV_AVG, racc[3] * INV_AVG);
        *(float4*)(orow + 4) = make_float4(racc[4] * INV_AVG, racc[5] * INV_AVG,
                                           racc[6] * INV_AVG, racc[7] * INV_AVG);
    } else {
        if (!any) return;
        float4 p0 = *(const float4*)(orow);
        float4 p1 = *(const float4*)(orow + 4);
        p0.x += racc[0] * INV_AVG; p0.y += racc[1] * INV_AVG;
        p0.z += racc[2] * INV_AVG; p0.w += racc[3] * INV_AVG;
        p1.x += racc[4] * INV_AVG; p1.y += racc[5] * INV_AVG;
        p1.z += racc[6] * INV_AVG; p1.w += racc[7] * INV_AVG;
        *(float4*)(orow)     = p0;
        *(float4*)(orow + 4) = p1;
    }
}

// ==================== last-resort fallback: atomic fused ====================

__global__ __launch_bounds__(256, 2)
void fused_mpconv_atomic(const float* __restrict__ node_scalars,
                         const float* __restrict__ node_vectors,
                         const float* __restrict__ edge_vec,
                         const float* __restrict__ sef,
                         const float* __restrict__ lengths,
                         const int* __restrict__ senders,
                         const int* __restrict__ receivers,
                         const float* __restrict__ W1, const float* __restrict__ b1,
                         const float* __restrict__ W2, const float* __restrict__ b2,
                         const float* __restrict__ W3, const float* __restrict__ b3,
                         float* __restrict__ out)
{
    __shared__ u16 A [EB * KP1];
    __shared__ u16 VS[EB * KV];
    __shared__ u16 Hb[EB * KH];
    __shared__ u16 Wt[2][128 * WTS];
    __shared__ float evl[3][EB];
    __shared__ int sidx[EB], ridx[EB];

    const int t = threadIdx.x;
    const int ebase = blockIdx.x * EB;

    {   const int e = t & 63, sub = t >> 6;
        const int eg = ebase + e; const bool ve = eg < N_EDGES;
        if (sub == 0)      sidx[e] = ve ? senders[eg] : 0;
        else if (sub == 1) ridx[e] = ve ? receivers[eg] : 0;
        else if (sub == 2) {
            evl[0][e] = ve ? edge_vec[(size_t)eg * 3 + 0] : 0.f;
            evl[1][e] = ve ? edge_vec[(size_t)eg * 3 + 1] : 0.f;
            evl[2][e] = ve ? edge_vec[(size_t)eg * 3 + 2] : 0.f;
        }
    }
    __syncthreads();

    {   const int me = t >> 2, q = t & 3;
        const int eg = ebase + me; const bool ve = eg < N_EDGES;
        const int si = sidx[me], ri = ridx[me];
        u16* Ar = A + me * KP1;
        stage16(node_scalars + (size_t)si * 64 + q * 16, Ar + q * 16,       ve);
        stage16(node_scalars + (size_t)ri * 64 + q * 16, Ar + 64 + q * 16,  ve);
        stage8 (sef          + (size_t)eg * 32 + q * 8,  Ar + 128 + q * 8,  ve);
        u16x8 zz = (u16x8)0;
        *(u16x8*)(Ar + 160 + q * 8) = zz;
        if (q == 0) *(u16x8*)(Ar + 192) = zz;
        stage16(node_vectors + (size_t)si * 96 + q * 24,      VS + me * KV + q * 24,      ve);
        stage8 (node_vectors + (size_t)si * 96 + q * 24 + 16, VS + me * KV + q * 24 + 16, ve);
        if (q == 0) Ar[160] = f2bf(ve ? lengths[eg] : 0.f);
    }
    __syncthreads();

    const int w  = t >> 6, l = t & 63;
    const int lr = l & 31;
    const int lg = l >> 5;
    const int m0 = (w >> 1) * 32;
    const int n0 = (w & 1) * 64;

    f32x16 acc0, acc1;
    const int n  = t & 127, ph = t >> 7;

    auto run_layer = [&](const u16* Asrc, int astr, const float* Wg, int Kr, int nsteps,
                         f32x16& a0, f32x16& a1) {
        #pragma unroll
        for (int i = 0; i < 16; ++i) { a0[i] = 0.f; a1[i] = 0.f; }
        #pragma unroll
        for (int i = 0; i < 4; ++i) {
            int kl = (i * 2 + ph) * 2;
            float v0 = (kl     < Kr) ? Wg[(size_t)kl * 128 + n]       : 0.f;
            float v1 = (kl + 1 < Kr) ? Wg[(size_t)(kl + 1) * 128 + n] : 0.f;
            unsigned pk = ((unsigned)f2bf(v1) << 16) | (unsigned)f2bf(v0);
            *(unsigned*)&Wt[0][n * WTS + kl] = pk;
        }
        __syncthreads();
        const u16* ap = Asrc + (m0 + lr) * astr + lg * 8;
        for (int ks = 0; ks < nsteps; ++ks) {
            const int cur = ks & 1;
            float v0[4], v1[4];
            const int kb = (ks + 1) * 16;
            if (ks + 1 < nsteps) {
                #pragma unroll
                for (int i = 0; i < 4; ++i) {
                    int kg = kb + (i * 2 + ph) * 2;
                    v0[i] = (kg     < Kr) ? Wg[(size_t)kg * 128 + n]       : 0.f;
                    v1[i] = (kg + 1 < Kr) ? Wg[(size_t)(kg + 1) * 128 + n] : 0.f;
                }
            }
            bf16x8 af = *(const bf16x8*)(ap + ks * 16);
            bf16x8 bf0 = *(const bf16x8*)(&Wt[cur][(n0      + lr) * WTS + lg * 8]);
            bf16x8 bf1 = *(const bf16x8*)(&Wt[cur][(n0 + 32 + lr) * WTS + lg * 8]);
            a0 = __builtin_amdgcn_mfma_f32_32x32x16_bf16(af, bf0, a0, 0, 0, 0);
            a1 = __builtin_amdgcn_mfma_f32_32x32x16_bf16(af, bf1, a1, 0, 0, 0);
            if (ks + 1 < nsteps) {
                #pragma unroll
                for (int i = 0; i < 4; ++i) {
                    int kl = (i * 2 + ph) * 2;
                    unsigned pk = ((unsigned)f2bf(v1[i]) << 16) | (unsigned)f2bf(v0[i]);
                    *(unsigned*)&Wt[cur ^ 1][n * WTS + kl] = pk;
                }
            }
            __syncthreads();
        }
    };

    run_layer(A, KP1, W1, 161, 11, acc0, acc1);
    {   const float bv0 = b1[n0 + lr], bv1 = b1[n0 + 32 + lr];
        #pragma unroll
        for (int r = 0; r < 16; ++r) {
            const int row = (r & 3) + 8 * (r >> 2) + 4 * lg;
            Hb[(m0 + row) * KH + n0 + lr]      = f2bf(fsilu(acc0[r] + bv0));
            Hb[(m0 + row) * KH + n0 + 32 + lr] = f2bf(fsilu(acc1[r] + bv1));
        }
    }
    __syncthreads();

    run_layer(Hb, KH, W2, 128, 8, acc0, acc1);
    __syncthreads();
    {   const float bv0 = b2[n0 + lr], bv1 = b2[n0 + 32 + lr];
        #pragma unroll
        for (int r = 0; r < 16; ++r) {
            const int row = (r & 3) + 8 * (r >> 2) + 4 * lg;
            Hb[(m0 + row) * KH + n0 + lr]      = f2bf(fsilu(acc0[r] + bv0));
            Hb[(m0 + row) * KH + n0 + 32 + lr] = f2bf(fsilu(acc1[r] + bv1));
        }
    }
    __syncthreads();

    run_layer(Hb, KH, W3, 128, 8, acc0, acc1);
    __syncthreads();
    {   const float bv0 = b3[n0 + lr], bv1 = b3[n0 + 32 + lr];
        #pragma unroll
        for (int r = 0; r < 16; ++r) {
            const int row = (r & 3) + 8 * (r >> 2) + 4 * lg;
            Hb[(m0 + row) * KH + n0 + lr]      = f2bf(acc0[r] + bv0);
            Hb[(m0 + row) * KH + n0 + 32 + lr] = f2bf(acc1[r] + bv1);
        }
    }
    __syncthreads();

    {   const int me = t >> 2, r = t & 3;
        const int eg2 = ebase + me;
        if (eg2 < N_EDGES) {
            const int row = ridx[me];
            const float evx = evl[0][me], evy = evl[1][me], evz = evl[2][me];
            float* orow = out + (size_t)row * OUTC;
            const u16* Ar = A  + me * KP1;
            const u16* Vr = VS + me * KV;
            const u16* Hr = Hb + me * KH;
            for (int col = r; col < OUTC; col += 4) {
                float val;
                if (col < 32) {
                    const int c = col;
                    const float vx = bf2f(Vr[3 * c]), vy = bf2f(Vr[3 * c + 1]), vz = bf2f(Vr[3 * c + 2]);
                    val = (vx * evx + vy * evy + vz * evz) * INV_SQ3 * bf2f(Hr[c]);
                } else {
                    const int idx = col - 32;
                    const int k = idx / 3;
                    const int d = idx - 3 * k;
                    const float g = bf2f(Hr[32 + k]);
                    if (k < 64) {
                        const float evd = (d == 0) ? evx : ((d == 1) ? evy : evz);
                        val = bf2f(Ar[k]) * evd * g;
                    } else {
                        const int c = k - 64;
                        const float vx = bf2f(Vr[3 * c]), vy = bf2f(Vr[3 * c + 1]), vz = bf2f(Vr[3 * c + 2]);
                        float cr;
                        if (d == 0)      cr = vy * evz - vz * evy;
                        else if (d == 1) cr = vz * evx - vx * evz;
                        else             cr = vx * evy - vy * evx;
                        val = cr * INV_SQ2 * g;
                    }
                }
                atomicAdd(&orow[col], val * INV_AVG);
            }
        }
    }
}

// ==================== launch ====================

extern "C" void kernel_launch(void* const* d_in, const int* in_sizes, int n_in,
                              void* d_out, int out_size, void* d_ws, size_t ws_size,
                              hipStream_t stream) {
    (void)in_sizes; (void)n_in;
    const float* node_scalars = (const float*)d_in[0];
    const float* node_vectors = (const float*)d_in[1];
    const float* edge_vec     = (const float*)d_in[2];
    const float* sef          = (const float*)d_in[3];
    const float* lengths      = (const float*)d_in[4];
    const int*   senders      = (const int*)d_in[5];
    const int*   receivers    = (const int*)d_in[6];
    const float* W1 = (const float*)d_in[7];
    const float* b1 = (const float*)d_in[8];
    const float* W2 = (const float*)d_in[9];
    const float* b2 = (const float*)d_in[10];
    const float* W3 = (const float*)d_in[11];
    const float* b3 = (const float*)d_in[12];
    float* out = (float*)d_out;

    auto align256 = [](size_t x) { return (x + 255) & ~(size_t)255; };

    // fixed CSR slabs at the front, msg chunk buffer takes the rest
    size_t off = 0;
    const size_t o_counts  = off; off += align256((size_t)N_NODES * sizeof(int));
    const size_t o_rowp    = off; off += align256((size_t)(N_NODES + 1) * sizeof(int));
    const size_t o_cursors = off; off += align256((size_t)(N_NODES + 1) * sizeof(int));
    const size_t o_part    = off; off += align256(64 * sizeof(int));
    const size_t o_elist   = off; off += align256((size_t)N_EDGES * sizeof(int));
    const size_t o_msg     = off;
    const size_t csr_bytes = off;

    // chunk capacity: Ec edges of 640B each, +64 rows tail slack, multiple of 64
    long Ec = 0;
    if (ws_size > csr_bytes + (size_t)128 * 640) {
        size_t cap_rows = (ws_size - csr_bytes) / 640;
        Ec = ((long)cap_rows - 64) / 64 * 64;
        if (Ec > N_EDGES) Ec = N_EDGES;
    }

    char* ws = (char*)d_ws;

    if (Ec >= 64 && (N_EDGES + Ec - 1) / Ec <= 64) {
        int* counts  = (int*)(ws + o_counts);
        int* rowp    = (int*)(ws + o_rowp);
        int* cursors = (int*)(ws + o_cursors);
        int* part    = (int*)(ws + o_part);
        int* elist   = (int*)(ws + o_elist);
        u16* msg     = (u16*)(ws + o_msg);

        hipMemsetAsync(counts, 0, (size_t)N_NODES * sizeof(int), stream);
        hist_kernel<<<(N_EDGES + 255) / 256, 256, 0, stream>>>(receivers, counts);
        scan_k1<<<NBLK1, 256, 0, stream>>>(counts, rowp, part);
        scan_k2<<<1, 64, 0, stream>>>(part);
        scan_k3<<<NBLK1, 256, 0, stream>>>(rowp, part, cursors);
        fill_kernel<<<(N_EDGES + 255) / 256, 256, 0, stream>>>(receivers, cursors, elist);

        const int nchunks = (int)((N_EDGES + Ec - 1) / Ec);
        const int ggrid = (N_NODES * 64 + 255) / 256;
        for (int c = 0; c < nchunks; ++c) {
            const int elo = (int)(c * Ec);
            const int cnt = (int)((N_EDGES - elo < Ec) ? (N_EDGES - elo) : Ec);
            const int ehi = elo + cnt;
            mlp_msg_kernel<<<(cnt + EB - 1) / EB, 256, 0, stream>>>(
                node_scalars, node_vectors, edge_vec, sef, lengths, senders, receivers,
                W1, b1, W2, b2, W3, b3, msg, elo, cnt);
            msg_gather_chunk<<<ggrid, 256, 0, stream>>>(
                rowp, elist, msg, out, elo, ehi, c == 0 ? 1 : 0);
        }
    } else {
        hipMemsetAsync(out, 0, (size_t)out_size * sizeof(float), stream);
        fused_mpconv_atomic<<<(N_EDGES + EB - 1) / EB, 256, 0, stream>>>(
            node_scalars, node_vectors, edge_vec, sef, lengths,
            senders, receivers, W1, b1, W2, b2, W3, b3, out);
    }
}

// Round 6
// 475.465 us; speedup vs baseline: 1.9811x; 1.5039x over previous
//
#include <hip/hip_runtime.h>

#define N_NODES 50000
#define N_EDGES 500000
#define EB 64
#define AST 184          // A row stride (bf16): 368B -> 8-lane perfect bank tiling
#define HST 136          // Hb row stride: 272B -> perfect tiling
#define W1K 176          // W1t row length (k padded 161->176)
#define OUTC 320
#define NBLK1 49
// fallback-kernel layout constants
#define KP1 200
#define KH  136
#define KV  104
#define WTS 40
#define INV_SQ3 0.57735026918962576f
#define INV_SQ2 0.70710678118654752f
#define INV_AVG 0.1f

typedef short bf16x8 __attribute__((ext_vector_type(8)));
typedef unsigned short u16;
typedef u16 u16x8 __attribute__((ext_vector_type(8)));
typedef float f32x16 __attribute__((ext_vector_type(16)));

template <int N> struct IC { static constexpr int val = N; };

__device__ __forceinline__ unsigned cvtpk(float lo, float hi) {
    unsigned r;
    asm("v_cvt_pk_bf16_f32 %0, %1, %2" : "=v"(r) : "v"(lo), "v"(hi));
    return r;
}
__device__ __forceinline__ u16 f2bf(float f) { return (u16)cvtpk(f, f); }
__device__ __forceinline__ float bf2f(u16 h) {
    union { unsigned u; float f; } x; x.u = ((unsigned)h) << 16; return x.f;
}
__device__ __forceinline__ float fsilu(float x) {
    return x * __builtin_amdgcn_rcpf(1.f + __expf(-x));
}

__device__ __forceinline__ void stage16(const float* g, u16* l, bool v) {
    float4 a0, a1, a2, a3;
    const float4 z = make_float4(0.f, 0.f, 0.f, 0.f);
    if (v) { a0 = *(const float4*)(g);     a1 = *(const float4*)(g + 4);
             a2 = *(const float4*)(g + 8); a3 = *(const float4*)(g + 12); }
    else   { a0 = z; a1 = z; a2 = z; a3 = z; }
    uint4 p0 = { cvtpk(a0.x, a0.y), cvtpk(a0.z, a0.w), cvtpk(a1.x, a1.y), cvtpk(a1.z, a1.w) };
    uint4 p1 = { cvtpk(a2.x, a2.y), cvtpk(a2.z, a2.w), cvtpk(a3.x, a3.y), cvtpk(a3.z, a3.w) };
    *(uint4*)(l) = p0; *(uint4*)(l + 8) = p1;
}
__device__ __forceinline__ void stage8(const float* g, u16* l, bool v) {
    float4 a0, a1;
    const float4 z = make_float4(0.f, 0.f, 0.f, 0.f);
    if (v) { a0 = *(const float4*)(g); a1 = *(const float4*)(g + 4); }
    else   { a0 = z; a1 = z; }
    uint4 p0 = { cvtpk(a0.x, a0.y), cvtpk(a0.z, a0.w), cvtpk(a1.x, a1.y), cvtpk(a1.z, a1.w) };
    *(uint4*)(l) = p0;
}

// ==================== CSR build ====================

__global__ void hist_kernel(const int* __restrict__ recv, int* __restrict__ counts) {
    const int e = blockIdx.x * 256 + threadIdx.x;
    if (e < N_EDGES) atomicAdd(&counts[recv[e]], 1);
}

__global__ __launch_bounds__(256) void scan_k1(const int* __restrict__ counts,
                                               int* __restrict__ rowp,
                                               int* __restrict__ partials) {
    __shared__ int sd[256];
    const int t = threadIdx.x;
    const int base = blockIdx.x * 1024 + t * 4;
    int c0 = 0, c1 = 0, c2 = 0, c3 = 0;
    if (base + 3 < N_NODES) {
        int4 v = *(const int4*)&counts[base];
        c0 = v.x; c1 = v.y; c2 = v.z; c3 = v.w;
    } else {
        if (base     < N_NODES) c0 = counts[base];
        if (base + 1 < N_NODES) c1 = counts[base + 1];
        if (base + 2 < N_NODES) c2 = counts[base + 2];
        if (base + 3 < N_NODES) c3 = counts[base + 3];
    }
    const int T = c0 + c1 + c2 + c3;
    sd[t] = T; __syncthreads();
    for (int off = 1; off < 256; off <<= 1) {
        int v = (t >= off) ? sd[t - off] : 0;
        __syncthreads();
        sd[t] += v;
        __syncthreads();
    }
    const int excl = sd[t] - T;
    if (base     < N_NODES) rowp[base]     = excl;
    if (base + 1 < N_NODES) rowp[base + 1] = excl + c0;
    if (base + 2 < N_NODES) rowp[base + 2] = excl + c0 + c1;
    if (base + 3 < N_NODES) rowp[base + 3] = excl + c0 + c1 + c2;
    if (t == 255) partials[blockIdx.x] = sd[255];
}

__global__ __launch_bounds__(64) void scan_k2(int* __restrict__ partials) {
    __shared__ int sd[64];
    const int t = threadIdx.x;
    const int v0 = (t < NBLK1) ? partials[t] : 0;
    sd[t] = v0; __syncthreads();
    for (int off = 1; off < 64; off <<= 1) {
        int v = (t >= off) ? sd[t - off] : 0;
        __syncthreads();
        sd[t] += v;
        __syncthreads();
    }
    if (t < NBLK1) partials[t] = sd[t] - v0;
}

__global__ __launch_bounds__(256) void scan_k3(int* __restrict__ rowp,
                                               const int* __restrict__ partials,
                                               int* __restrict__ cursors) {
    const int add = partials[blockIdx.x];
    const int base = blockIdx.x * 1024 + threadIdx.x * 4;
    #pragma unroll
    for (int i = 0; i < 4; ++i) {
        const int idx = base + i;
        if (idx < N_NODES) {
            const int v = rowp[idx] + add;
            rowp[idx] = v;
            cursors[idx] = v;
        }
    }
    if (blockIdx.x == 0 && threadIdx.x == 0) rowp[N_NODES] = N_EDGES;
}

__global__ void fill_kernel(const int* __restrict__ recv,
                            int* __restrict__ cursors, int* __restrict__ elist) {
    const int e = blockIdx.x * 256 + threadIdx.x;
    if (e < N_EDGES) {
        const int r = recv[e];
        const int pos = atomicAdd(&cursors[r], 1);
        elist[pos] = e;
    }
}

// ==================== weight pre-conversion: W[k][n] f32 -> Wt[n][k] bf16 ====================

#define WT_TOTAL (128 * W1K + 2 * 128 * 128)

__global__ __launch_bounds__(256)
void wcvt_kernel(const float* __restrict__ W1, const float* __restrict__ W2,
                 const float* __restrict__ W3, u16* __restrict__ wt) {
    const int i = blockIdx.x * 256 + threadIdx.x;
    if (i < 128 * W1K) {
        const int n = i / W1K, k = i - n * W1K;
        wt[i] = (k < 161) ? f2bf(W1[(size_t)k * 128 + n]) : (u16)0;
    } else if (i < 128 * W1K + 128 * 128) {
        const int j = i - 128 * W1K;
        const int n = j >> 7, k = j & 127;
        wt[i] = f2bf(W2[(size_t)k * 128 + n]);
    } else if (i < WT_TOTAL) {
        const int j = i - 128 * W1K - 128 * 128;
        const int n = j >> 7, k = j & 127;
        wt[i] = f2bf(W3[(size_t)k * 128 + n]);
    }
}

// ==================== phase E: MLP + message epilogue, CSR-slot ordered ====================
// processes CSR slots [slo, slo+cnt); edge id = elist[slot]; writes msg[slot-slo][320]

__global__ __launch_bounds__(256, 3)
void mlp_msg_kernel(const float* __restrict__ node_scalars,
                    const float* __restrict__ node_vectors,
                    const float* __restrict__ edge_vec,
                    const float* __restrict__ sef,
                    const float* __restrict__ lengths,
                    const int* __restrict__ senders,
                    const int* __restrict__ receivers,
                    const int* __restrict__ elist,
                    const u16* __restrict__ wt,
                    const float* __restrict__ b1,
                    const float* __restrict__ b2,
                    const float* __restrict__ b3,
                    u16* __restrict__ msg, int slo, int cnt)
{
    __shared__ u16 A [EB * AST];   // [edge][k]: 0..63 s_snd, 64..159 r_snd/sef -> v_snd, 160 len, 161..175 zero
    __shared__ u16 Hb[EB * HST];
    __shared__ float evl[3][EB];
    __shared__ int sidx[EB];

    const int t = threadIdx.x;
    const int lbase = blockIdx.x * EB;
    const int me = t >> 2, q = t & 3;
    const int ls = lbase + me;
    const bool ve = ls < cnt;
    const int eid = ve ? elist[slo + ls] : 0;

    {   const int si = ve ? senders[eid] : 0;
        const int ri = ve ? receivers[eid] : 0;
        u16* Ar = A + me * AST;
        stage16(node_scalars + (size_t)si * 64 + q * 16, Ar + q * 16,      ve);
        stage16(node_scalars + (size_t)ri * 64 + q * 16, Ar + 64 + q * 16, ve);
        stage8 (sef          + (size_t)eid * 32 + q * 8, Ar + 128 + q * 8, ve);
        if (q == 0) {
            u16x8 z8 = (u16x8)0;
            z8[0] = ve ? f2bf(lengths[eid]) : (u16)0;
            *(u16x8*)(Ar + 160) = z8;
            sidx[me] = si;
            evl[0][me] = ve ? edge_vec[(size_t)eid * 3 + 0] : 0.f;
            evl[1][me] = ve ? edge_vec[(size_t)eid * 3 + 1] : 0.f;
            evl[2][me] = ve ? edge_vec[(size_t)eid * 3 + 2] : 0.f;
        } else if (q == 1) {
            u16x8 z8 = (u16x8)0;
            *(u16x8*)(Ar + 168) = z8;
        }
    }
    __syncthreads();

    const int w  = t >> 6, l = t & 63;
    const int lr = l & 31;
    const int lg = l >> 5;
    const int m0 = (w >> 1) * 32;
    const int n0 = (w & 1) * 64;

    const u16* w1t = wt;
    const u16* w2t = wt + 128 * W1K;
    const u16* w3t = w2t + 128 * 128;

    f32x16 acc0, acc1;

    auto run_layer = [&](const u16* Asrc, int astr, const u16* Wg, int wstr, auto NS,
                         f32x16& a0, f32x16& a1) {
        #pragma unroll
        for (int i = 0; i < 16; ++i) { a0[i] = 0.f; a1[i] = 0.f; }
        const u16* ap  = Asrc + (m0 + lr) * astr + lg * 8;
        const u16* bp0 = Wg + (size_t)(n0 + lr) * wstr + lg * 8;
        const u16* bp1 = bp0 + 32 * wstr;
        #pragma unroll
        for (int ks = 0; ks < NS.val; ++ks) {
            bf16x8 af  = *(const bf16x8*)(ap  + ks * 16);
            bf16x8 bv0 = *(const bf16x8*)(bp0 + ks * 16);
            bf16x8 bv1 = *(const bf16x8*)(bp1 + ks * 16);
            a0 = __builtin_amdgcn_mfma_f32_32x32x16_bf16(af, bv0, a0, 0, 0, 0);
            a1 = __builtin_amdgcn_mfma_f32_32x32x16_bf16(af, bv1, a1, 0, 0, 0);
        }
    };

    // ---------- layer 1 ----------
    run_layer(A, AST, w1t, W1K, IC<11>{}, acc0, acc1);
    __syncthreads();   // all A-reads complete
    {   const float bv0 = b1[n0 + lr], bv1 = b1[n0 + 32 + lr];
        #pragma unroll
        for (int r = 0; r < 16; ++r) {
            const int row = (r & 3) + 8 * (r >> 2) + 4 * lg;
            Hb[(m0 + row) * HST + n0 + lr]      = f2bf(fsilu(acc0[r] + bv0));
            Hb[(m0 + row) * HST + n0 + 32 + lr] = f2bf(fsilu(acc1[r] + bv1));
        }
    }
    {   // stage v_snd into A rows 64..159 (dead after layer 1)
        const int si = sidx[me];
        stage16(node_vectors + (size_t)si * 96 + q * 24,      A + me * AST + 64 + q * 24,      ve);
        stage8 (node_vectors + (size_t)si * 96 + q * 24 + 16, A + me * AST + 64 + q * 24 + 16, ve);
    }
    __syncthreads();

    // ---------- layer 2 ----------
    run_layer(Hb, HST, w2t, 128, IC<8>{}, acc0, acc1);
    __syncthreads();
    {   const float bv0 = b2[n0 + lr], bv1 = b2[n0 + 32 + lr];
        #pragma unroll
        for (int r = 0; r < 16; ++r) {
            const int row = (r & 3) + 8 * (r >> 2) + 4 * lg;
            Hb[(m0 + row) * HST + n0 + lr]      = f2bf(fsilu(acc0[r] + bv0));
            Hb[(m0 + row) * HST + n0 + 32 + lr] = f2bf(fsilu(acc1[r] + bv1));
        }
    }
    __syncthreads();

    // ---------- layer 3 (mix) ----------
    run_layer(Hb, HST, w3t, 128, IC<8>{}, acc0, acc1);
    __syncthreads();
    {   const float bv0 = b3[n0 + lr], bv1 = b3[n0 + 32 + lr];
        #pragma unroll
        for (int r = 0; r < 16; ++r) {
            const int row = (r & 3) + 8 * (r >> 2) + 4 * lg;
            Hb[(m0 + row) * HST + n0 + lr]      = f2bf(acc0[r] + bv0);
            Hb[(m0 + row) * HST + n0 + 32 + lr] = f2bf(acc1[r] + bv1);
        }
    }
    __syncthreads();

    // ---------- message epilogue: 4 threads/edge, write msg row at CSR slot ----------
    if (ve) {
        const u16* Ar = A  + me * AST;
        const u16* Vr = Ar + 64;
        const u16* Hr = Hb + me * HST;
        u16* mrow = msg + (size_t)ls * 320;
        const float evx = evl[0][me], evy = evl[1][me], evz = evl[2][me];

        {   // m0 block: cols 8q..8q+7
            float f[8];
            #pragma unroll
            for (int j = 0; j < 8; ++j) {
                const int c = 8 * q + j;
                const float vx = bf2f(Vr[3 * c]), vy = bf2f(Vr[3 * c + 1]), vz = bf2f(Vr[3 * c + 2]);
                f[j] = (vx * evx + vy * evy + vz * evz) * INV_SQ3 * bf2f(Hr[c]);
            }
            uint4 o = { cvtpk(f[0], f[1]), cvtpk(f[2], f[3]), cvtpk(f[4], f[5]), cvtpk(f[6], f[7]) };
            *(uint4*)(mrow + 8 * q) = o;
        }
        #pragma unroll
        for (int gg = 0; gg < 3; ++gg) {
            float fb[24];
            #pragma unroll
            for (int g8 = 0; g8 < 8; ++g8) {
                const int k = 24 * q + gg * 8 + g8;
                const float gate = bf2f(Hr[32 + k]);
                if (k < 64) {
                    const float s = bf2f(Ar[k]) * gate;
                    fb[3 * g8 + 0] = s * evx;
                    fb[3 * g8 + 1] = s * evy;
                    fb[3 * g8 + 2] = s * evz;
                } else {
                    const int c = k - 64;
                    const float vx = bf2f(Vr[3 * c]), vy = bf2f(Vr[3 * c + 1]), vz = bf2f(Vr[3 * c + 2]);
                    const float sc = INV_SQ2 * gate;
                    fb[3 * g8 + 0] = (vy * evz - vz * evy) * sc;
                    fb[3 * g8 + 1] = (vz * evx - vx * evz) * sc;
                    fb[3 * g8 + 2] = (vx * evy - vy * evx) * sc;
                }
            }
            u16* dst = mrow + 32 + 72 * q + 24 * gg;
            uint4 o0 = { cvtpk(fb[0],  fb[1]),  cvtpk(fb[2],  fb[3]),  cvtpk(fb[4],  fb[5]),  cvtpk(fb[6],  fb[7])  };
            uint4 o1 = { cvtpk(fb[8],  fb[9]),  cvtpk(fb[10], fb[11]), cvtpk(fb[12], fb[13]), cvtpk(fb[14], fb[15]) };
            uint4 o2 = { cvtpk(fb[16], fb[17]), cvtpk(fb[18], fb[19]), cvtpk(fb[20], fb[21]), cvtpk(fb[22], fb[23]) };
            *(uint4*)(dst)      = o0;
            *(uint4*)(dst + 8)  = o1;
            *(uint4*)(dst + 16) = o2;
        }
    }
}

// ==================== phase 2: sequential streaming gather ====================
// msg rows are in CSR order: node gw owns slots [rowp[gw], rowp[gw+1])

__global__ __launch_bounds__(256)
void msg_gather_seq(const int* __restrict__ rowp,
                    const u16* __restrict__ msg,
                    float* __restrict__ out,
                    int slo, int shi, int first)
{
    const int gw = (blockIdx.x * 256 + threadIdx.x) >> 6;   // node
    const int l  = threadIdx.x & 63;
    if (gw >= N_NODES || l >= 40) return;

    const int rp0 = rowp[gw], rp1 = rowp[gw + 1];
    const int lo = rp0 > slo ? rp0 : slo;
    const int hi = rp1 < shi ? rp1 : shi;
    const int n  = hi - lo;

    float acc[8] = {0.f, 0.f, 0.f, 0.f, 0.f, 0.f, 0.f, 0.f};
    const u16* mb = msg + (size_t)(lo - slo) * 320 + l * 8;

    int j = 0;
    for (; j + 1 < n; j += 2) {
        const u16x8 v0 = *(const u16x8*)(mb + (size_t)j * 320);
        const u16x8 v1 = *(const u16x8*)(mb + (size_t)(j + 1) * 320);
        #pragma unroll
        for (int qq = 0; qq < 8; ++qq) acc[qq] += bf2f(v0[qq]) + bf2f(v1[qq]);
    }
    if (j < n) {
        const u16x8 v0 = *(const u16x8*)(mb + (size_t)j * 320);
        #pragma unroll
        for (int qq = 0; qq < 8; ++qq) acc[qq] += bf2f(v0[qq]);
    }

    float* orow = out + (size_t)gw * OUTC + l * 8;
    if (first) {
        *(float4*)(orow)     = make_float4(acc[0] * INV_AVG, acc[1] * INV_AVG,
                                           acc[2] * INV_AVG, acc[3] * INV_AVG);
        *(float4*)(orow + 4) = make_float4(acc[4] * INV_AVG, acc[5] * INV_AVG,
                                           acc[6] * INV_AVG, acc[7] * INV_AVG);
    } else if (n > 0) {
        float4 p0 = *(const float4*)(orow);
        float4 p1 = *(const float4*)(orow + 4);
        p0.x += acc[0] * INV_AVG; p0.y += acc[1] * INV_AVG;
        p0.z += acc[2] * INV_AVG; p0.w += acc[3] * INV_AVG;
        p1.x += acc[4] * INV_AVG; p1.y += acc[5] * INV_AVG;
        p1.z += acc[6] * INV_AVG; p1.w += acc[7] * INV_AVG;
        *(float4*)(orow)     = p0;
        *(float4*)(orow + 4) = p1;
    }
}

// ==================== last-resort fallback: atomic fused (round-2 design) ====================

__global__ __launch_bounds__(256, 2)
void fused_mpconv_atomic(const float* __restrict__ node_scalars,
                         const float* __restrict__ node_vectors,
                         const float* __restrict__ edge_vec,
                         const float* __restrict__ sef,
                         const float* __restrict__ lengths,
                         const int* __restrict__ senders,
                         const int* __restrict__ receivers,
                         const float* __restrict__ W1, const float* __restrict__ b1,
                         const float* __restrict__ W2, const float* __restrict__ b2,
                         const float* __restrict__ W3, const float* __restrict__ b3,
                         float* __restrict__ out)
{
    __shared__ u16 A [EB * KP1];
    __shared__ u16 VS[EB * KV];
    __shared__ u16 Hb[EB * KH];
    __shared__ u16 Wt[2][128 * WTS];
    __shared__ float evl[3][EB];
    __shared__ int sidx[EB], ridx[EB];

    const int t = threadIdx.x;
    const int ebase = blockIdx.x * EB;

    {   const int e = t & 63, sub = t >> 6;
        const int eg = ebase + e; const bool ve = eg < N_EDGES;
        if (sub == 0)      sidx[e] = ve ? senders[eg] : 0;
        else if (sub == 1) ridx[e] = ve ? receivers[eg] : 0;
        else if (sub == 2) {
            evl[0][e] = ve ? edge_vec[(size_t)eg * 3 + 0] : 0.f;
            evl[1][e] = ve ? edge_vec[(size_t)eg * 3 + 1] : 0.f;
            evl[2][e] = ve ? edge_vec[(size_t)eg * 3 + 2] : 0.f;
        }
    }
    __syncthreads();

    {   const int me = t >> 2, q = t & 3;
        const int eg = ebase + me; const bool ve = eg < N_EDGES;
        const int si = sidx[me], ri = ridx[me];
        u16* Ar = A + me * KP1;
        stage16(node_scalars + (size_t)si * 64 + q * 16, Ar + q * 16,       ve);
        stage16(node_scalars + (size_t)ri * 64 + q * 16, Ar + 64 + q * 16,  ve);
        stage8 (sef          + (size_t)eg * 32 + q * 8,  Ar + 128 + q * 8,  ve);
        u16x8 zz = (u16x8)0;
        *(u16x8*)(Ar + 160 + q * 8) = zz;
        if (q == 0) *(u16x8*)(Ar + 192) = zz;
        stage16(node_vectors + (size_t)si * 96 + q * 24,      VS + me * KV + q * 24,      ve);
        stage8 (node_vectors + (size_t)si * 96 + q * 24 + 16, VS + me * KV + q * 24 + 16, ve);
        if (q == 0) Ar[160] = f2bf(ve ? lengths[eg] : 0.f);
    }
    __syncthreads();

    const int w  = t >> 6, l = t & 63;
    const int lr = l & 31;
    const int lg = l >> 5;
    const int m0 = (w >> 1) * 32;
    const int n0 = (w & 1) * 64;

    f32x16 acc0, acc1;
    const int n  = t & 127, ph = t >> 7;

    auto run_layer = [&](const u16* Asrc, int astr, const float* Wg, int Kr, int nsteps,
                         f32x16& a0, f32x16& a1) {
        #pragma unroll
        for (int i = 0; i < 16; ++i) { a0[i] = 0.f; a1[i] = 0.f; }
        #pragma unroll
        for (int i = 0; i < 4; ++i) {
            int kl = (i * 2 + ph) * 2;
            float v0 = (kl     < Kr) ? Wg[(size_t)kl * 128 + n]       : 0.f;
            float v1 = (kl + 1 < Kr) ? Wg[(size_t)(kl + 1) * 128 + n] : 0.f;
            *(unsigned*)&Wt[0][n * WTS + kl] = cvtpk(v0, v1);
        }
        __syncthreads();
        const u16* ap = Asrc + (m0 + lr) * astr + lg * 8;
        for (int ks = 0; ks < nsteps; ++ks) {
            const int cur = ks & 1;
            float v0[4], v1[4];
            const int kb = (ks + 1) * 16;
            if (ks + 1 < nsteps) {
                #pragma unroll
                for (int i = 0; i < 4; ++i) {
                    int kg = kb + (i * 2 + ph) * 2;
                    v0[i] = (kg     < Kr) ? Wg[(size_t)kg * 128 + n]       : 0.f;
                    v1[i] = (kg + 1 < Kr) ? Wg[(size_t)(kg + 1) * 128 + n] : 0.f;
                }
            }
            bf16x8 af = *(const bf16x8*)(ap + ks * 16);
            bf16x8 bf0 = *(const bf16x8*)(&Wt[cur][(n0      + lr) * WTS + lg * 8]);
            bf16x8 bf1 = *(const bf16x8*)(&Wt[cur][(n0 + 32 + lr) * WTS + lg * 8]);
            a0 = __builtin_amdgcn_mfma_f32_32x32x16_bf16(af, bf0, a0, 0, 0, 0);
            a1 = __builtin_amdgcn_mfma_f32_32x32x16_bf16(af, bf1, a1, 0, 0, 0);
            if (ks + 1 < nsteps) {
                #pragma unroll
                for (int i = 0; i < 4; ++i) {
                    int kl = (i * 2 + ph) * 2;
                    *(unsigned*)&Wt[cur ^ 1][n * WTS + kl] = cvtpk(v0[i], v1[i]);
                }
            }
            __syncthreads();
        }
    };

    run_layer(A, KP1, W1, 161, 11, acc0, acc1);
    {   const float bv0 = b1[n0 + lr], bv1 = b1[n0 + 32 + lr];
        #pragma unroll
        for (int r = 0; r < 16; ++r) {
            const int row = (r & 3) + 8 * (r >> 2) + 4 * lg;
            Hb[(m0 + row) * KH + n0 + lr]      = f2bf(fsilu(acc0[r] + bv0));
            Hb[(m0 + row) * KH + n0 + 32 + lr] = f2bf(fsilu(acc1[r] + bv1));
        }
    }
    __syncthreads();

    run_layer(Hb, KH, W2, 128, 8, acc0, acc1);
    __syncthreads();
    {   const float bv0 = b2[n0 + lr], bv1 = b2[n0 + 32 + lr];
        #pragma unroll
        for (int r = 0; r < 16; ++r) {
            const int row = (r & 3) + 8 * (r >> 2) + 4 * lg;
            Hb[(m0 + row) * KH + n0 + lr]      = f2bf(fsilu(acc0[r] + bv0));
            Hb[(m0 + row) * KH + n0 + 32 + lr] = f2bf(fsilu(acc1[r] + bv1));
        }
    }
    __syncthreads();

    run_layer(Hb, KH, W3, 128, 8, acc0, acc1);
    __syncthreads();
    {   const float bv0 = b3[n0 + lr], bv1 = b3[n0 + 32 + lr];
        #pragma unroll
        for (int r = 0; r < 16; ++r) {
            const int row = (r & 3) + 8 * (r >> 2) + 4 * lg;
            Hb[(m0 + row) * KH + n0 + lr]      = f2bf(acc0[r] + bv0);
            Hb[(m0 + row) * KH + n0 + 32 + lr] = f2bf(acc1[r] + bv1);
        }
    }
    __syncthreads();

    {   const int me = t >> 2, r = t & 3;
        const int eg2 = ebase + me;
        if (eg2 < N_EDGES) {
            const int row = ridx[me];
            const float evx = evl[0][me], evy = evl[1][me], evz = evl[2][me];
            float* orow = out + (size_t)row * OUTC;
            const u16* Ar = A  + me * KP1;
            const u16* Vr = VS + me * KV;
            const u16* Hr = Hb + me * KH;
            for (int col = r; col < OUTC; col += 4) {
                float val;
                if (col < 32) {
                    const int c = col;
                    const float vx = bf2f(Vr[3 * c]), vy = bf2f(Vr[3 * c + 1]), vz = bf2f(Vr[3 * c + 2]);
                    val = (vx * evx + vy * evy + vz * evz) * INV_SQ3 * bf2f(Hr[c]);
                } else {
                    const int idx = col - 32;
                    const int k = idx / 3;
                    const int d = idx - 3 * k;
                    const float g = bf2f(Hr[32 + k]);
                    if (k < 64) {
                        const float evd = (d == 0) ? evx : ((d == 1) ? evy : evz);
                        val = bf2f(Ar[k]) * evd * g;
                    } else {
                        const int c = k - 64;
                        const float vx = bf2f(Vr[3 * c]), vy = bf2f(Vr[3 * c + 1]), vz = bf2f(Vr[3 * c + 2]);
                        float cr;
                        if (d == 0)      cr = vy * evz - vz * evy;
                        else if (d == 1) cr = vz * evx - vx * evz;
                        else             cr = vx * evy - vy * evx;
                        val = cr * INV_SQ2 * g;
                    }
                }
                atomicAdd(&orow[col], val * INV_AVG);
            }
        }
    }
}

// ==================== launch ====================

extern "C" void kernel_launch(void* const* d_in, const int* in_sizes, int n_in,
                              void* d_out, int out_size, void* d_ws, size_t ws_size,
                              hipStream_t stream) {
    (void)in_sizes; (void)n_in;
    const float* node_scalars = (const float*)d_in[0];
    const float* node_vectors = (const float*)d_in[1];
    const float* edge_vec     = (const float*)d_in[2];
    const float* sef          = (const float*)d_in[3];
    const float* lengths      = (const float*)d_in[4];
    const int*   senders      = (const int*)d_in[5];
    const int*   receivers    = (const int*)d_in[6];
    const float* W1 = (const float*)d_in[7];
    const float* b1 = (const float*)d_in[8];
    const float* W2 = (const float*)d_in[9];
    const float* b2 = (const float*)d_in[10];
    const float* W3 = (const float*)d_in[11];
    const float* b3 = (const float*)d_in[12];
    float* out = (float*)d_out;

    auto align256 = [](size_t x) { return (x + 255) & ~(size_t)255; };

    size_t off = 0;
    const size_t o_counts  = off; off += align256((size_t)N_NODES * sizeof(int));
    const size_t o_rowp    = off; off += align256((size_t)(N_NODES + 1) * sizeof(int));
    const size_t o_cursors = off; off += align256((size_t)(N_NODES + 1) * sizeof(int));
    const size_t o_part    = off; off += align256(64 * sizeof(int));
    const size_t o_elist   = off; off += align256((size_t)N_EDGES * sizeof(int));
    const size_t o_wt      = off; off += align256((size_t)WT_TOTAL * sizeof(u16));
    const size_t o_msg     = off;
    const size_t fixed_bytes = off;

    long Ec = 0;
    if (ws_size > fixed_bytes + (size_t)128 * 640) {
        size_t cap_rows = (ws_size - fixed_bytes) / 640;
        Ec = ((long)cap_rows - 64) / 64 * 64;
        if (Ec > N_EDGES) Ec = N_EDGES;
    }

    char* ws = (char*)d_ws;

    if (Ec >= 64) {
        int* counts  = (int*)(ws + o_counts);
        int* rowp    = (int*)(ws + o_rowp);
        int* cursors = (int*)(ws + o_cursors);
        int* part    = (int*)(ws + o_part);
        int* elist   = (int*)(ws + o_elist);
        u16* wt      = (u16*)(ws + o_wt);
        u16* msg     = (u16*)(ws + o_msg);

        hipMemsetAsync(counts, 0, (size_t)N_NODES * sizeof(int), stream);
        hist_kernel<<<(N_EDGES + 255) / 256, 256, 0, stream>>>(receivers, counts);
        scan_k1<<<NBLK1, 256, 0, stream>>>(counts, rowp, part);
        scan_k2<<<1, 64, 0, stream>>>(part);
        scan_k3<<<NBLK1, 256, 0, stream>>>(rowp, part, cursors);
        fill_kernel<<<(N_EDGES + 255) / 256, 256, 0, stream>>>(receivers, cursors, elist);
        wcvt_kernel<<<(WT_TOTAL + 255) / 256, 256, 0, stream>>>(W1, W2, W3, wt);

        const int nchunks = (int)((N_EDGES + Ec - 1) / Ec);
        const int ggrid = (N_NODES * 64 + 255) / 256;
        for (int c = 0; c < nchunks; ++c) {
            const int slo = (int)(c * Ec);
            const int cnt = (int)((N_EDGES - slo < Ec) ? (N_EDGES - slo) : Ec);
            mlp_msg_kernel<<<(cnt + EB - 1) / EB, 256, 0, stream>>>(
                node_scalars, node_vectors, edge_vec, sef, lengths, senders, receivers,
                elist, wt, b1, b2, b3, msg, slo, cnt);
            msg_gather_seq<<<ggrid, 256, 0, stream>>>(
                rowp, msg, out, slo, slo + cnt, c == 0 ? 1 : 0);
        }
    } else {
        hipMemsetAsync(out, 0, (size_t)out_size * sizeof(float), stream);
        fused_mpconv_atomic<<<(N_EDGES + EB - 1) / EB, 256, 0, stream>>>(
            node_scalars, node_vectors, edge_vec, sef, lengths,
            senders, receivers, W1, b1, W2, b2, W3, b3, out);
    }
}

// Round 7
// 444.280 us; speedup vs baseline: 2.1202x; 1.0702x over previous
//
#include <hip/hip_runtime.h>

#define N_NODES 50000
#define N_EDGES 500000
#define EB 64
#define AST 184          // A row stride (bf16): 368B -> 8-way bank spread for b128 reads
#define HST 136          // Hb row stride: cols 0..127 data, 128..135 ev/si stash (never MFMA'd)
#define W1K 176          // W1t row length (k padded 161->176, weights zeroed beyond 160)
#define OUTC 320
#define NBLK1 49
// fallback-kernel layout constants
#define KP1 200
#define KH  136
#define KV  104
#define WTS 40
#define INV_SQ3 0.57735026918962576f
#define INV_SQ2 0.70710678118654752f
#define INV_AVG 0.1f

typedef short bf16x8 __attribute__((ext_vector_type(8)));
typedef unsigned short u16;
typedef u16 u16x8 __attribute__((ext_vector_type(8)));
typedef float f32x16 __attribute__((ext_vector_type(16)));

template <int N> struct IC { static constexpr int val = N; };

__device__ __forceinline__ unsigned cvtpk(float lo, float hi) {
    unsigned r;
    asm("v_cvt_pk_bf16_f32 %0, %1, %2" : "=v"(r) : "v"(lo), "v"(hi));
    return r;
}
__device__ __forceinline__ u16 f2bf(float f) { return (u16)cvtpk(f, f); }
__device__ __forceinline__ float bf2f(u16 h) {
    union { unsigned u; float f; } x; x.u = ((unsigned)h) << 16; return x.f;
}
__device__ __forceinline__ float fsilu(float x) {
    return x * __builtin_amdgcn_rcpf(1.f + __expf(-x));
}

__device__ __forceinline__ void stage16(const float* g, u16* l, bool v) {
    float4 a0, a1, a2, a3;
    const float4 z = make_float4(0.f, 0.f, 0.f, 0.f);
    if (v) { a0 = *(const float4*)(g);     a1 = *(const float4*)(g + 4);
             a2 = *(const float4*)(g + 8); a3 = *(const float4*)(g + 12); }
    else   { a0 = z; a1 = z; a2 = z; a3 = z; }
    uint4 p0 = { cvtpk(a0.x, a0.y), cvtpk(a0.z, a0.w), cvtpk(a1.x, a1.y), cvtpk(a1.z, a1.w) };
    uint4 p1 = { cvtpk(a2.x, a2.y), cvtpk(a2.z, a2.w), cvtpk(a3.x, a3.y), cvtpk(a3.z, a3.w) };
    *(uint4*)(l) = p0; *(uint4*)(l + 8) = p1;
}
__device__ __forceinline__ void stage8(const float* g, u16* l, bool v) {
    float4 a0, a1;
    const float4 z = make_float4(0.f, 0.f, 0.f, 0.f);
    if (v) { a0 = *(const float4*)(g); a1 = *(const float4*)(g + 4); }
    else   { a0 = z; a1 = z; }
    uint4 p0 = { cvtpk(a0.x, a0.y), cvtpk(a0.z, a0.w), cvtpk(a1.x, a1.y), cvtpk(a1.z, a1.w) };
    *(uint4*)(l) = p0;
}

// ==================== CSR build ====================

__global__ void hist_kernel(const int* __restrict__ recv, int* __restrict__ counts) {
    const int e = blockIdx.x * 256 + threadIdx.x;
    if (e < N_EDGES) atomicAdd(&counts[recv[e]], 1);
}

__global__ __launch_bounds__(256) void scan_k1(const int* __restrict__ counts,
                                               int* __restrict__ rowp,
                                               int* __restrict__ partials) {
    __shared__ int sd[256];
    const int t = threadIdx.x;
    const int base = blockIdx.x * 1024 + t * 4;
    int c0 = 0, c1 = 0, c2 = 0, c3 = 0;
    if (base + 3 < N_NODES) {
        int4 v = *(const int4*)&counts[base];
        c0 = v.x; c1 = v.y; c2 = v.z; c3 = v.w;
    } else {
        if (base     < N_NODES) c0 = counts[base];
        if (base + 1 < N_NODES) c1 = counts[base + 1];
        if (base + 2 < N_NODES) c2 = counts[base + 2];
        if (base + 3 < N_NODES) c3 = counts[base + 3];
    }
    const int T = c0 + c1 + c2 + c3;
    sd[t] = T; __syncthreads();
    for (int off = 1; off < 256; off <<= 1) {
        int v = (t >= off) ? sd[t - off] : 0;
        __syncthreads();
        sd[t] += v;
        __syncthreads();
    }
    const int excl = sd[t] - T;
    if (base     < N_NODES) rowp[base]     = excl;
    if (base + 1 < N_NODES) rowp[base + 1] = excl + c0;
    if (base + 2 < N_NODES) rowp[base + 2] = excl + c0 + c1;
    if (base + 3 < N_NODES) rowp[base + 3] = excl + c0 + c1 + c2;
    if (t == 255) partials[blockIdx.x] = sd[255];
}

__global__ __launch_bounds__(64) void scan_k2(int* __restrict__ partials) {
    __shared__ int sd[64];
    const int t = threadIdx.x;
    const int v0 = (t < NBLK1) ? partials[t] : 0;
    sd[t] = v0; __syncthreads();
    for (int off = 1; off < 64; off <<= 1) {
        int v = (t >= off) ? sd[t - off] : 0;
        __syncthreads();
        sd[t] += v;
        __syncthreads();
    }
    if (t < NBLK1) partials[t] = sd[t] - v0;
}

__global__ __launch_bounds__(256) void scan_k3(int* __restrict__ rowp,
                                               const int* __restrict__ partials,
                                               int* __restrict__ cursors) {
    const int add = partials[blockIdx.x];
    const int base = blockIdx.x * 1024 + threadIdx.x * 4;
    #pragma unroll
    for (int i = 0; i < 4; ++i) {
        const int idx = base + i;
        if (idx < N_NODES) {
            const int v = rowp[idx] + add;
            rowp[idx] = v;
            cursors[idx] = v;
        }
    }
    if (blockIdx.x == 0 && threadIdx.x == 0) rowp[N_NODES] = N_EDGES;
}

__global__ void fill_kernel(const int* __restrict__ recv,
                            int* __restrict__ cursors, int* __restrict__ elist) {
    const int e = blockIdx.x * 256 + threadIdx.x;
    if (e < N_EDGES) {
        const int r = recv[e];
        const int pos = atomicAdd(&cursors[r], 1);
        elist[pos] = e;
    }
}

// ==================== weight pre-conversion: W[k][n] f32 -> Wt[n][k] bf16 ====================

#define WT_TOTAL (128 * W1K + 2 * 128 * 128)

__global__ __launch_bounds__(256)
void wcvt_kernel(const float* __restrict__ W1, const float* __restrict__ W2,
                 const float* __restrict__ W3, u16* __restrict__ wt) {
    const int i = blockIdx.x * 256 + threadIdx.x;
    if (i < 128 * W1K) {
        const int n = i / W1K, k = i - n * W1K;
        wt[i] = (k < 161) ? f2bf(W1[(size_t)k * 128 + n]) : (u16)0;
    } else if (i < 128 * W1K + 128 * 128) {
        const int j = i - 128 * W1K;
        const int n = j >> 7, k = j & 127;
        wt[i] = f2bf(W2[(size_t)k * 128 + n]);
    } else if (i < WT_TOTAL) {
        const int j = i - 128 * W1K - 128 * 128;
        const int n = j >> 7, k = j & 127;
        wt[i] = f2bf(W3[(size_t)k * 128 + n]);
    }
}

// ==================== node feature pre-conversion to bf16 tables ====================

#define NS_ELEMS (N_NODES * 64)
#define NV_ELEMS (N_NODES * 96)

__global__ __launch_bounds__(256)
void nodecvt_kernel(const float* __restrict__ ns, const float* __restrict__ nv,
                    u16* __restrict__ nsb, u16* __restrict__ nvb) {
    const int i2 = (blockIdx.x * 256 + threadIdx.x) * 2;
    if (i2 < NS_ELEMS) {
        float2 v = *(const float2*)(ns + i2);
        *(unsigned*)(nsb + i2) = cvtpk(v.x, v.y);
    } else if (i2 < NS_ELEMS + NV_ELEMS) {
        const int j2 = i2 - NS_ELEMS;
        float2 v = *(const float2*)(nv + j2);
        *(unsigned*)(nvb + j2) = cvtpk(v.x, v.y);
    }
}

// ==================== phase E: MLP + message epilogue, CSR-slot ordered ====================
// LDS = A(23552) + Hb(17408) = 40960B exactly -> 4 blocks/CU.
// Hb cols 128..135 per edge row stash {ev.x,ev.y,ev.z as raw f32 bits, si} - never MFMA input.
// A cols 161..175 zeroed (W1t zero there; must avoid NaN-bit junk reaching MFMA).

__global__ __launch_bounds__(256, 4)
void mlp_msg_kernel(const u16* __restrict__ ns_bf,
                    const u16* __restrict__ nv_bf,
                    const float* __restrict__ edge_vec,
                    const float* __restrict__ sef,
                    const float* __restrict__ lengths,
                    const int* __restrict__ senders,
                    const int* __restrict__ receivers,
                    const int* __restrict__ elist,
                    const u16* __restrict__ wt,
                    const float* __restrict__ b1,
                    const float* __restrict__ b2,
                    const float* __restrict__ b3,
                    u16* __restrict__ msg, int slo, int cnt)
{
    __shared__ u16 A [EB * AST];
    __shared__ u16 Hb[EB * HST];

    const int t = threadIdx.x;
    const int lbase = blockIdx.x * EB;
    const int me = t >> 2, q = t & 3;
    const int ls = lbase + me;
    const bool ve = ls < cnt;
    const int eid = ve ? elist[slo + ls] : 0;

    {   const int si = senders[eid];
        const int ri = receivers[eid];
        u16* Ar = A + me * AST;
        const u16* srow = ns_bf + (size_t)si * 64 + q * 16;
        const u16* rrow = ns_bf + (size_t)ri * 64 + q * 16;
        *(u16x8*)(Ar + q * 16)          = *(const u16x8*)(srow);
        *(u16x8*)(Ar + q * 16 + 8)      = *(const u16x8*)(srow + 8);
        *(u16x8*)(Ar + 64 + q * 16)     = *(const u16x8*)(rrow);
        *(u16x8*)(Ar + 64 + q * 16 + 8) = *(const u16x8*)(rrow + 8);
        stage8(sef + (size_t)eid * 32 + q * 8, Ar + 128 + q * 8, true);
        if (q == 0) {
            u16x8 z8 = (u16x8)0;
            z8[0] = f2bf(lengths[eid]);
            *(u16x8*)(Ar + 160) = z8;                 // len + zero cols 161..167
            const float evx = edge_vec[(size_t)eid * 3 + 0];
            const float evy = edge_vec[(size_t)eid * 3 + 1];
            const float evz = edge_vec[(size_t)eid * 3 + 2];
            const unsigned bx = __builtin_bit_cast(unsigned, evx);
            const unsigned by = __builtin_bit_cast(unsigned, evy);
            const unsigned bz = __builtin_bit_cast(unsigned, evz);
            u16x8 p;
            p[0] = (u16)(bx & 0xFFFF); p[1] = (u16)(bx >> 16);
            p[2] = (u16)(by & 0xFFFF); p[3] = (u16)(by >> 16);
            p[4] = (u16)(bz & 0xFFFF); p[5] = (u16)(bz >> 16);
            p[6] = (u16)si;            p[7] = 0;
            *(u16x8*)(Hb + me * HST + 128) = p;
        } else if (q == 1) {
            *(u16x8*)(A + me * AST + 168) = (u16x8)0; // zero cols 168..175
        }
    }
    __syncthreads();

    const int w  = t >> 6, l = t & 63;
    const int lr = l & 31;
    const int lg = l >> 5;
    const int m0 = (w >> 1) * 32;
    const int n0 = (w & 1) * 64;

    const u16* w1t = wt;
    const u16* w2t = wt + 128 * W1K;
    const u16* w3t = w2t + 128 * 128;

    f32x16 acc0, acc1;

    auto run_layer = [&](const u16* Asrc, int astr, const u16* Wg, int wstr, auto NS,
                         f32x16& a0, f32x16& a1) {
        #pragma unroll
        for (int i = 0; i < 16; ++i) { a0[i] = 0.f; a1[i] = 0.f; }
        const u16* ap  = Asrc + (m0 + lr) * astr + lg * 8;
        const u16* bp0 = Wg + (size_t)(n0 + lr) * wstr + lg * 8;
        const u16* bp1 = bp0 + 32 * wstr;
        #pragma unroll
        for (int ks = 0; ks < NS.val; ++ks) {
            bf16x8 af  = *(const bf16x8*)(ap  + ks * 16);
            bf16x8 bv0 = *(const bf16x8*)(bp0 + ks * 16);
            bf16x8 bv1 = *(const bf16x8*)(bp1 + ks * 16);
            a0 = __builtin_amdgcn_mfma_f32_32x32x16_bf16(af, bv0, a0, 0, 0, 0);
            a1 = __builtin_amdgcn_mfma_f32_32x32x16_bf16(af, bv1, a1, 0, 0, 0);
        }
    };

    // ---------- layer 1 ----------
    run_layer(A, AST, w1t, W1K, IC<11>{}, acc0, acc1);
    __syncthreads();   // all A-reads complete
    {   const float bv0 = b1[n0 + lr], bv1 = b1[n0 + 32 + lr];
        #pragma unroll
        for (int r = 0; r < 16; ++r) {
            const int row = (r & 3) + 8 * (r >> 2) + 4 * lg;
            Hb[(m0 + row) * HST + n0 + lr]      = f2bf(fsilu(acc0[r] + bv0));
            Hb[(m0 + row) * HST + n0 + 32 + lr] = f2bf(fsilu(acc1[r] + bv1));
        }
    }
    {   // stage v_snd (bf16 table) into A rows 64..159 (dead after layer 1)
        const int si2 = (int)Hb[me * HST + 134];
        const u16* src = nv_bf + (size_t)si2 * 96 + q * 24;
        u16* dst = A + me * AST + 64 + q * 24;
        *(u16x8*)(dst)      = *(const u16x8*)(src);
        *(u16x8*)(dst + 8)  = *(const u16x8*)(src + 8);
        *(u16x8*)(dst + 16) = *(const u16x8*)(src + 16);
    }
    __syncthreads();

    // ---------- layer 2 ----------
    run_layer(Hb, HST, w2t, 128, IC<8>{}, acc0, acc1);
    __syncthreads();
    {   const float bv0 = b2[n0 + lr], bv1 = b2[n0 + 32 + lr];
        #pragma unroll
        for (int r = 0; r < 16; ++r) {
            const int row = (r & 3) + 8 * (r >> 2) + 4 * lg;
            Hb[(m0 + row) * HST + n0 + lr]      = f2bf(fsilu(acc0[r] + bv0));
            Hb[(m0 + row) * HST + n0 + 32 + lr] = f2bf(fsilu(acc1[r] + bv1));
        }
    }
    __syncthreads();

    // ---------- layer 3 (mix) ----------
    run_layer(Hb, HST, w3t, 128, IC<8>{}, acc0, acc1);
    __syncthreads();
    {   const float bv0 = b3[n0 + lr], bv1 = b3[n0 + 32 + lr];
        #pragma unroll
        for (int r = 0; r < 16; ++r) {
            const int row = (r & 3) + 8 * (r >> 2) + 4 * lg;
            Hb[(m0 + row) * HST + n0 + lr]      = f2bf(acc0[r] + bv0);
            Hb[(m0 + row) * HST + n0 + 32 + lr] = f2bf(acc1[r] + bv1);
        }
    }
    __syncthreads();

    // ---------- message epilogue: 4 threads/edge, write msg row at CSR slot ----------
    if (ve) {
        const u16* Ar = A  + me * AST;
        const u16* Vr = Ar + 64;
        const u16* Hr = Hb + me * HST;
        const u16* Er = Hr + 128;
        u16* mrow = msg + (size_t)ls * 320;
        const float evx = __builtin_bit_cast(float, (unsigned)Er[0] | ((unsigned)Er[1] << 16));
        const float evy = __builtin_bit_cast(float, (unsigned)Er[2] | ((unsigned)Er[3] << 16));
        const float evz = __builtin_bit_cast(float, (unsigned)Er[4] | ((unsigned)Er[5] << 16));

        {   // m0 block: cols 8q..8q+7
            float f[8];
            #pragma unroll
            for (int j = 0; j < 8; ++j) {
                const int c = 8 * q + j;
                const float vx = bf2f(Vr[3 * c]), vy = bf2f(Vr[3 * c + 1]), vz = bf2f(Vr[3 * c + 2]);
                f[j] = (vx * evx + vy * evy + vz * evz) * INV_SQ3 * bf2f(Hr[c]);
            }
            uint4 o = { cvtpk(f[0], f[1]), cvtpk(f[2], f[3]), cvtpk(f[4], f[5]), cvtpk(f[6], f[7]) };
            *(uint4*)(mrow + 8 * q) = o;
        }
        #pragma unroll
        for (int gg = 0; gg < 3; ++gg) {
            float fb[24];
            #pragma unroll
            for (int g8 = 0; g8 < 8; ++g8) {
                const int k = 24 * q + gg * 8 + g8;
                const float gate = bf2f(Hr[32 + k]);
                if (k < 64) {
                    const float s = bf2f(Ar[k]) * gate;
                    fb[3 * g8 + 0] = s * evx;
                    fb[3 * g8 + 1] = s * evy;
                    fb[3 * g8 + 2] = s * evz;
                } else {
                    const int c = k - 64;
                    const float vx = bf2f(Vr[3 * c]), vy = bf2f(Vr[3 * c + 1]), vz = bf2f(Vr[3 * c + 2]);
                    const float sc = INV_SQ2 * gate;
                    fb[3 * g8 + 0] = (vy * evz - vz * evy) * sc;
                    fb[3 * g8 + 1] = (vz * evx - vx * evz) * sc;
                    fb[3 * g8 + 2] = (vx * evy - vy * evx) * sc;
                }
            }
            u16* dst = mrow + 32 + 72 * q + 24 * gg;
            uint4 o0 = { cvtpk(fb[0],  fb[1]),  cvtpk(fb[2],  fb[3]),  cvtpk(fb[4],  fb[5]),  cvtpk(fb[6],  fb[7])  };
            uint4 o1 = { cvtpk(fb[8],  fb[9]),  cvtpk(fb[10], fb[11]), cvtpk(fb[12], fb[13]), cvtpk(fb[14], fb[15]) };
            uint4 o2 = { cvtpk(fb[16], fb[17]), cvtpk(fb[18], fb[19]), cvtpk(fb[20], fb[21]), cvtpk(fb[22], fb[23]) };
            *(uint4*)(dst)      = o0;
            *(uint4*)(dst + 8)  = o1;
            *(uint4*)(dst + 16) = o2;
        }
    }
}

// ==================== phase 2: sequential streaming gather ====================

__global__ __launch_bounds__(256)
void msg_gather_seq(const int* __restrict__ rowp,
                    const u16* __restrict__ msg,
                    float* __restrict__ out,
                    int slo, int shi, int first)
{
    const int gw = (blockIdx.x * 256 + threadIdx.x) >> 6;   // node
    const int l  = threadIdx.x & 63;
    if (gw >= N_NODES || l >= 40) return;

    const int rp0 = rowp[gw], rp1 = rowp[gw + 1];
    const int lo = rp0 > slo ? rp0 : slo;
    const int hi = rp1 < shi ? rp1 : shi;
    const int n  = hi - lo;

    float acc[8] = {0.f, 0.f, 0.f, 0.f, 0.f, 0.f, 0.f, 0.f};
    const u16* mb = msg + (size_t)(lo - slo) * 320 + l * 8;

    int j = 0;
    for (; j + 3 < n; j += 4) {
        const u16x8 v0 = *(const u16x8*)(mb + (size_t)(j)     * 320);
        const u16x8 v1 = *(const u16x8*)(mb + (size_t)(j + 1) * 320);
        const u16x8 v2 = *(const u16x8*)(mb + (size_t)(j + 2) * 320);
        const u16x8 v3 = *(const u16x8*)(mb + (size_t)(j + 3) * 320);
        #pragma unroll
        for (int qq = 0; qq < 8; ++qq)
            acc[qq] += (bf2f(v0[qq]) + bf2f(v1[qq])) + (bf2f(v2[qq]) + bf2f(v3[qq]));
    }
    for (; j < n; ++j) {
        const u16x8 v0 = *(const u16x8*)(mb + (size_t)j * 320);
        #pragma unroll
        for (int qq = 0; qq < 8; ++qq) acc[qq] += bf2f(v0[qq]);
    }

    float* orow = out + (size_t)gw * OUTC + l * 8;
    if (first) {
        *(float4*)(orow)     = make_float4(acc[0] * INV_AVG, acc[1] * INV_AVG,
                                           acc[2] * INV_AVG, acc[3] * INV_AVG);
        *(float4*)(orow + 4) = make_float4(acc[4] * INV_AVG, acc[5] * INV_AVG,
                                           acc[6] * INV_AVG, acc[7] * INV_AVG);
    } else if (n > 0) {
        float4 p0 = *(const float4*)(orow);
        float4 p1 = *(const float4*)(orow + 4);
        p0.x += acc[0] * INV_AVG; p0.y += acc[1] * INV_AVG;
        p0.z += acc[2] * INV_AVG; p0.w += acc[3] * INV_AVG;
        p1.x += acc[4] * INV_AVG; p1.y += acc[5] * INV_AVG;
        p1.z += acc[6] * INV_AVG; p1.w += acc[7] * INV_AVG;
        *(float4*)(orow)     = p0;
        *(float4*)(orow + 4) = p1;
    }
}

// ==================== last-resort fallback: atomic fused ====================

__global__ __launch_bounds__(256, 2)
void fused_mpconv_atomic(const float* __restrict__ node_scalars,
                         const float* __restrict__ node_vectors,
                         const float* __restrict__ edge_vec,
                         const float* __restrict__ sef,
                         const float* __restrict__ lengths,
                         const int* __restrict__ senders,
                         const int* __restrict__ receivers,
                         const float* __restrict__ W1, const float* __restrict__ b1,
                         const float* __restrict__ W2, const float* __restrict__ b2,
                         const float* __restrict__ W3, const float* __restrict__ b3,
                         float* __restrict__ out)
{
    __shared__ u16 A [EB * KP1];
    __shared__ u16 VS[EB * KV];
    __shared__ u16 Hb[EB * KH];
    __shared__ u16 Wt[2][128 * WTS];
    __shared__ float evl[3][EB];
    __shared__ int sidx[EB], ridx[EB];

    const int t = threadIdx.x;
    const int ebase = blockIdx.x * EB;

    {   const int e = t & 63, sub = t >> 6;
        const int eg = ebase + e; const bool ve = eg < N_EDGES;
        if (sub == 0)      sidx[e] = ve ? senders[eg] : 0;
        else if (sub == 1) ridx[e] = ve ? receivers[eg] : 0;
        else if (sub == 2) {
            evl[0][e] = ve ? edge_vec[(size_t)eg * 3 + 0] : 0.f;
            evl[1][e] = ve ? edge_vec[(size_t)eg * 3 + 1] : 0.f;
            evl[2][e] = ve ? edge_vec[(size_t)eg * 3 + 2] : 0.f;
        }
    }
    __syncthreads();

    {   const int me = t >> 2, q = t & 3;
        const int eg = ebase + me; const bool ve = eg < N_EDGES;
        const int si = sidx[me], ri = ridx[me];
        u16* Ar = A + me * KP1;
        stage16(node_scalars + (size_t)si * 64 + q * 16, Ar + q * 16,       ve);
        stage16(node_scalars + (size_t)ri * 64 + q * 16, Ar + 64 + q * 16,  ve);
        stage8 (sef          + (size_t)eg * 32 + q * 8,  Ar + 128 + q * 8,  ve);
        u16x8 zz = (u16x8)0;
        *(u16x8*)(Ar + 160 + q * 8) = zz;
        if (q == 0) *(u16x8*)(Ar + 192) = zz;
        stage16(node_vectors + (size_t)si * 96 + q * 24,      VS + me * KV + q * 24,      ve);
        stage8 (node_vectors + (size_t)si * 96 + q * 24 + 16, VS + me * KV + q * 24 + 16, ve);
        if (q == 0) Ar[160] = f2bf(ve ? lengths[eg] : 0.f);
    }
    __syncthreads();

    const int w  = t >> 6, l = t & 63;
    const int lr = l & 31;
    const int lg = l >> 5;
    const int m0 = (w >> 1) * 32;
    const int n0 = (w & 1) * 64;

    f32x16 acc0, acc1;
    const int n  = t & 127, ph = t >> 7;

    auto run_layer = [&](const u16* Asrc, int astr, const float* Wg, int Kr, int nsteps,
                         f32x16& a0, f32x16& a1) {
        #pragma unroll
        for (int i = 0; i < 16; ++i) { a0[i] = 0.f; a1[i] = 0.f; }
        #pragma unroll
        for (int i = 0; i < 4; ++i) {
            int kl = (i * 2 + ph) * 2;
            float v0 = (kl     < Kr) ? Wg[(size_t)kl * 128 + n]       : 0.f;
            float v1 = (kl + 1 < Kr) ? Wg[(size_t)(kl + 1) * 128 + n] : 0.f;
            *(unsigned*)&Wt[0][n * WTS + kl] = cvtpk(v0, v1);
        }
        __syncthreads();
        const u16* ap = Asrc + (m0 + lr) * astr + lg * 8;
        for (int ks = 0; ks < nsteps; ++ks) {
            const int cur = ks & 1;
            float v0[4], v1[4];
            const int kb = (ks + 1) * 16;
            if (ks + 1 < nsteps) {
                #pragma unroll
                for (int i = 0; i < 4; ++i) {
                    int kg = kb + (i * 2 + ph) * 2;
                    v0[i] = (kg     < Kr) ? Wg[(size_t)kg * 128 + n]       : 0.f;
                    v1[i] = (kg + 1 < Kr) ? Wg[(size_t)(kg + 1) * 128 + n] : 0.f;
                }
            }
            bf16x8 af = *(const bf16x8*)(ap + ks * 16);
            bf16x8 bf0 = *(const bf16x8*)(&Wt[cur][(n0      + lr) * WTS + lg * 8]);
            bf16x8 bf1 = *(const bf16x8*)(&Wt[cur][(n0 + 32 + lr) * WTS + lg * 8]);
            a0 = __builtin_amdgcn_mfma_f32_32x32x16_bf16(af, bf0, a0, 0, 0, 0);
            a1 = __builtin_amdgcn_mfma_f32_32x32x16_bf16(af, bf1, a1, 0, 0, 0);
            if (ks + 1 < nsteps) {
                #pragma unroll
                for (int i = 0; i < 4; ++i) {
                    int kl = (i * 2 + ph) * 2;
                    *(unsigned*)&Wt[cur ^ 1][n * WTS + kl] = cvtpk(v0[i], v1[i]);
                }
            }
            __syncthreads();
        }
    };

    run_layer(A, KP1, W1, 161, 11, acc0, acc1);
    {   const float bv0 = b1[n0 + lr], bv1 = b1[n0 + 32 + lr];
        #pragma unroll
        for (int r = 0; r < 16; ++r) {
            const int row = (r & 3) + 8 * (r >> 2) + 4 * lg;
            Hb[(m0 + row) * KH + n0 + lr]      = f2bf(fsilu(acc0[r] + bv0));
            Hb[(m0 + row) * KH + n0 + 32 + lr] = f2bf(fsilu(acc1[r] + bv1));
        }
    }
    __syncthreads();

    run_layer(Hb, KH, W2, 128, 8, acc0, acc1);
    __syncthreads();
    {   const float bv0 = b2[n0 + lr], bv1 = b2[n0 + 32 + lr];
        #pragma unroll
        for (int r = 0; r < 16; ++r) {
            const int row = (r & 3) + 8 * (r >> 2) + 4 * lg;
            Hb[(m0 + row) * KH + n0 + lr]      = f2bf(fsilu(acc0[r] + bv0));
            Hb[(m0 + row) * KH + n0 + 32 + lr] = f2bf(fsilu(acc1[r] + bv1));
        }
    }
    __syncthreads();

    run_layer(Hb, KH, W3, 128, 8, acc0, acc1);
    __syncthreads();
    {   const float bv0 = b3[n0 + lr], bv1 = b3[n0 + 32 + lr];
        #pragma unroll
        for (int r = 0; r < 16; ++r) {
            const int row = (r & 3) + 8 * (r >> 2) + 4 * lg;
            Hb[(m0 + row) * KH + n0 + lr]      = f2bf(acc0[r] + bv0);
            Hb[(m0 + row) * KH + n0 + 32 + lr] = f2bf(acc1[r] + bv1);
        }
    }
    __syncthreads();

    {   const int me = t >> 2, r = t & 3;
        const int eg2 = ebase + me;
        if (eg2 < N_EDGES) {
            const int row = ridx[me];
            const float evx = evl[0][me], evy = evl[1][me], evz = evl[2][me];
            float* orow = out + (size_t)row * OUTC;
            const u16* Ar = A  + me * KP1;
            const u16* Vr = VS + me * KV;
            const u16* Hr = Hb + me * KH;
            for (int col = r; col < OUTC; col += 4) {
                float val;
                if (col < 32) {
                    const int c = col;
                    const float vx = bf2f(Vr[3 * c]), vy = bf2f(Vr[3 * c + 1]), vz = bf2f(Vr[3 * c + 2]);
                    val = (vx * evx + vy * evy + vz * evz) * INV_SQ3 * bf2f(Hr[c]);
                } else {
                    const int idx = col - 32;
                    const int k = idx / 3;
                    const int d = idx - 3 * k;
                    const float g = bf2f(Hr[32 + k]);
                    if (k < 64) {
                        const float evd = (d == 0) ? evx : ((d == 1) ? evy : evz);
                        val = bf2f(Ar[k]) * evd * g;
                    } else {
                        const int c = k - 64;
                        const float vx = bf2f(Vr[3 * c]), vy = bf2f(Vr[3 * c + 1]), vz = bf2f(Vr[3 * c + 2]);
                        float cr;
                        if (d == 0)      cr = vy * evz - vz * evy;
                        else if (d == 1) cr = vz * evx - vx * evz;
                        else             cr = vx * evy - vy * evx;
                        val = cr * INV_SQ2 * g;
                    }
                }
                atomicAdd(&orow[col], val * INV_AVG);
            }
        }
    }
}

// ==================== launch ====================

extern "C" void kernel_launch(void* const* d_in, const int* in_sizes, int n_in,
                              void* d_out, int out_size, void* d_ws, size_t ws_size,
                              hipStream_t stream) {
    (void)in_sizes; (void)n_in;
    const float* node_scalars = (const float*)d_in[0];
    const float* node_vectors = (const float*)d_in[1];
    const float* edge_vec     = (const float*)d_in[2];
    const float* sef          = (const float*)d_in[3];
    const float* lengths      = (const float*)d_in[4];
    const int*   senders      = (const int*)d_in[5];
    const int*   receivers    = (const int*)d_in[6];
    const float* W1 = (const float*)d_in[7];
    const float* b1 = (const float*)d_in[8];
    const float* W2 = (const float*)d_in[9];
    const float* b2 = (const float*)d_in[10];
    const float* W3 = (const float*)d_in[11];
    const float* b3 = (const float*)d_in[12];
    float* out = (float*)d_out;

    auto align256 = [](size_t x) { return (x + 255) & ~(size_t)255; };

    size_t off = 0;
    const size_t o_counts  = off; off += align256((size_t)N_NODES * sizeof(int));
    const size_t o_rowp    = off; off += align256((size_t)(N_NODES + 1) * sizeof(int));
    const size_t o_cursors = off; off += align256((size_t)(N_NODES + 1) * sizeof(int));
    const size_t o_part    = off; off += align256(64 * sizeof(int));
    const size_t o_elist   = off; off += align256((size_t)N_EDGES * sizeof(int));
    const size_t o_wt      = off; off += align256((size_t)WT_TOTAL * sizeof(u16));
    const size_t o_nsb     = off; off += align256((size_t)NS_ELEMS * sizeof(u16));
    const size_t o_nvb     = off; off += align256((size_t)NV_ELEMS * sizeof(u16));
    const size_t o_msg     = off;
    const size_t fixed_bytes = off;

    long Ec = 0;
    if (ws_size > fixed_bytes + (size_t)128 * 640) {
        size_t cap_rows = (ws_size - fixed_bytes) / 640;
        Ec = ((long)cap_rows - 64) / 64 * 64;
        if (Ec > N_EDGES) Ec = N_EDGES;
    }

    char* ws = (char*)d_ws;

    if (Ec >= 64) {
        int* counts  = (int*)(ws + o_counts);
        int* rowp    = (int*)(ws + o_rowp);
        int* cursors = (int*)(ws + o_cursors);
        int* part    = (int*)(ws + o_part);
        int* elist   = (int*)(ws + o_elist);
        u16* wt      = (u16*)(ws + o_wt);
        u16* nsb     = (u16*)(ws + o_nsb);
        u16* nvb     = (u16*)(ws + o_nvb);
        u16* msg     = (u16*)(ws + o_msg);

        hipMemsetAsync(counts, 0, (size_t)N_NODES * sizeof(int), stream);
        hist_kernel<<<(N_EDGES + 255) / 256, 256, 0, stream>>>(receivers, counts);
        scan_k1<<<NBLK1, 256, 0, stream>>>(counts, rowp, part);
        scan_k2<<<1, 64, 0, stream>>>(part);
        scan_k3<<<NBLK1, 256, 0, stream>>>(rowp, part, cursors);
        fill_kernel<<<(N_EDGES + 255) / 256, 256, 0, stream>>>(receivers, cursors, elist);
        wcvt_kernel<<<(WT_TOTAL + 255) / 256, 256, 0, stream>>>(W1, W2, W3, wt);
        nodecvt_kernel<<<((NS_ELEMS + NV_ELEMS) / 2 + 255) / 256, 256, 0, stream>>>(
            node_scalars, node_vectors, nsb, nvb);

        const int nchunks = (int)((N_EDGES + Ec - 1) / Ec);
        const int ggrid = (N_NODES * 64 + 255) / 256;
        for (int c = 0; c < nchunks; ++c) {
            const int slo = (int)(c * Ec);
            const int cnt = (int)((N_EDGES - slo < Ec) ? (N_EDGES - slo) : Ec);
            mlp_msg_kernel<<<(cnt + EB - 1) / EB, 256, 0, stream>>>(
                nsb, nvb, edge_vec, sef, lengths, senders, receivers,
                elist, wt, b1, b2, b3, msg, slo, cnt);
            msg_gather_seq<<<ggrid, 256, 0, stream>>>(
                rowp, msg, out, slo, slo + cnt, c == 0 ? 1 : 0);
        }
    } else {
        hipMemsetAsync(out, 0, (size_t)out_size * sizeof(float), stream);
        fused_mpconv_atomic<<<(N_EDGES + EB - 1) / EB, 256, 0, stream>>>(
            node_scalars, node_vectors, edge_vec, sef, lengths,
            senders, receivers, W1, b1, W2, b2, W3, b3, out);
    }
}

// Round 8
// 375.628 us; speedup vs baseline: 2.5077x; 1.1828x over previous
//
#include <hip/hip_runtime.h>

#define N_NODES 50000
#define N_EDGES 500000
#define EB 64
#define AST 184          // A row stride (bf16): 368B -> 8-way bank spread for b128 reads
#define HST 136          // Hb row stride: cols 0..127 data, 128..135 ev/si stash (never MFMA'd)
#define W1K 176          // W1t row length (k padded 161->176, weights zeroed beyond 160)
#define OUTC 320
#define MROW 208         // msg row: [m0 32 | sg 64 | m1b 96 | ev 3xf32=6 | pad 10] u16 = 416B
#define NBLK1 49
// fallback-kernel layout constants
#define KP1 200
#define KH  136
#define KV  104
#define WTS 40
#define INV_SQ3 0.57735026918962576f
#define INV_SQ2 0.70710678118654752f
#define INV_AVG 0.1f

typedef short bf16x8 __attribute__((ext_vector_type(8)));
typedef unsigned short u16;
typedef u16 u16x8 __attribute__((ext_vector_type(8)));
typedef float f32x16 __attribute__((ext_vector_type(16)));

template <int N> struct IC { static constexpr int val = N; };

__device__ __forceinline__ unsigned cvtpk(float lo, float hi) {
    unsigned r;
    asm("v_cvt_pk_bf16_f32 %0, %1, %2" : "=v"(r) : "v"(lo), "v"(hi));
    return r;
}
__device__ __forceinline__ u16 f2bf(float f) { return (u16)cvtpk(f, f); }
__device__ __forceinline__ float bf2f(u16 h) {
    union { unsigned u; float f; } x; x.u = ((unsigned)h) << 16; return x.f;
}
__device__ __forceinline__ float fsilu(float x) {
    return x * __builtin_amdgcn_rcpf(1.f + __expf(-x));
}

__device__ __forceinline__ void stage16(const float* g, u16* l, bool v) {
    float4 a0, a1, a2, a3;
    const float4 z = make_float4(0.f, 0.f, 0.f, 0.f);
    if (v) { a0 = *(const float4*)(g);     a1 = *(const float4*)(g + 4);
             a2 = *(const float4*)(g + 8); a3 = *(const float4*)(g + 12); }
    else   { a0 = z; a1 = z; a2 = z; a3 = z; }
    uint4 p0 = { cvtpk(a0.x, a0.y), cvtpk(a0.z, a0.w), cvtpk(a1.x, a1.y), cvtpk(a1.z, a1.w) };
    uint4 p1 = { cvtpk(a2.x, a2.y), cvtpk(a2.z, a2.w), cvtpk(a3.x, a3.y), cvtpk(a3.z, a3.w) };
    *(uint4*)(l) = p0; *(uint4*)(l + 8) = p1;
}
__device__ __forceinline__ void stage8(const float* g, u16* l, bool v) {
    float4 a0, a1;
    const float4 z = make_float4(0.f, 0.f, 0.f, 0.f);
    if (v) { a0 = *(const float4*)(g); a1 = *(const float4*)(g + 4); }
    else   { a0 = z; a1 = z; }
    uint4 p0 = { cvtpk(a0.x, a0.y), cvtpk(a0.z, a0.w), cvtpk(a1.x, a1.y), cvtpk(a1.z, a1.w) };
    *(uint4*)(l) = p0;
}

// ==================== CSR build ====================

__global__ void hist_kernel(const int* __restrict__ recv, int* __restrict__ counts) {
    const int e = blockIdx.x * 256 + threadIdx.x;
    if (e < N_EDGES) atomicAdd(&counts[recv[e]], 1);
}

__global__ __launch_bounds__(256) void scan_k1(const int* __restrict__ counts,
                                               int* __restrict__ rowp,
                                               int* __restrict__ partials) {
    __shared__ int sd[256];
    const int t = threadIdx.x;
    const int base = blockIdx.x * 1024 + t * 4;
    int c0 = 0, c1 = 0, c2 = 0, c3 = 0;
    if (base + 3 < N_NODES) {
        int4 v = *(const int4*)&counts[base];
        c0 = v.x; c1 = v.y; c2 = v.z; c3 = v.w;
    } else {
        if (base     < N_NODES) c0 = counts[base];
        if (base + 1 < N_NODES) c1 = counts[base + 1];
        if (base + 2 < N_NODES) c2 = counts[base + 2];
        if (base + 3 < N_NODES) c3 = counts[base + 3];
    }
    const int T = c0 + c1 + c2 + c3;
    sd[t] = T; __syncthreads();
    for (int off = 1; off < 256; off <<= 1) {
        int v = (t >= off) ? sd[t - off] : 0;
        __syncthreads();
        sd[t] += v;
        __syncthreads();
    }
    const int excl = sd[t] - T;
    if (base     < N_NODES) rowp[base]     = excl;
    if (base + 1 < N_NODES) rowp[base + 1] = excl + c0;
    if (base + 2 < N_NODES) rowp[base + 2] = excl + c0 + c1;
    if (base + 3 < N_NODES) rowp[base + 3] = excl + c0 + c1 + c2;
    if (t == 255) partials[blockIdx.x] = sd[255];
}

__global__ __launch_bounds__(64) void scan_k2(int* __restrict__ partials) {
    __shared__ int sd[64];
    const int t = threadIdx.x;
    const int v0 = (t < NBLK1) ? partials[t] : 0;
    sd[t] = v0; __syncthreads();
    for (int off = 1; off < 64; off <<= 1) {
        int v = (t >= off) ? sd[t - off] : 0;
        __syncthreads();
        sd[t] += v;
        __syncthreads();
    }
    if (t < NBLK1) partials[t] = sd[t] - v0;
}

__global__ __launch_bounds__(256) void scan_k3(int* __restrict__ rowp,
                                               const int* __restrict__ partials,
                                               int* __restrict__ cursors) {
    const int add = partials[blockIdx.x];
    const int base = blockIdx.x * 1024 + threadIdx.x * 4;
    #pragma unroll
    for (int i = 0; i < 4; ++i) {
        const int idx = base + i;
        if (idx < N_NODES) {
            const int v = rowp[idx] + add;
            rowp[idx] = v;
            cursors[idx] = v;
        }
    }
    if (blockIdx.x == 0 && threadIdx.x == 0) rowp[N_NODES] = N_EDGES;
}

__global__ void fill_kernel(const int* __restrict__ recv,
                            int* __restrict__ cursors, int* __restrict__ elist) {
    const int e = blockIdx.x * 256 + threadIdx.x;
    if (e < N_EDGES) {
        const int r = recv[e];
        const int pos = atomicAdd(&cursors[r], 1);
        elist[pos] = e;
    }
}

// ==================== weight pre-conversion: W[k][n] f32 -> Wt[n][k] bf16 ====================

#define WT_TOTAL (128 * W1K + 2 * 128 * 128)

__global__ __launch_bounds__(256)
void wcvt_kernel(const float* __restrict__ W1, const float* __restrict__ W2,
                 const float* __restrict__ W3, u16* __restrict__ wt) {
    const int i = blockIdx.x * 256 + threadIdx.x;
    if (i < 128 * W1K) {
        const int n = i / W1K, k = i - n * W1K;
        wt[i] = (k < 161) ? f2bf(W1[(size_t)k * 128 + n]) : (u16)0;
    } else if (i < 128 * W1K + 128 * 128) {
        const int j = i - 128 * W1K;
        const int n = j >> 7, k = j & 127;
        wt[i] = f2bf(W2[(size_t)k * 128 + n]);
    } else if (i < WT_TOTAL) {
        const int j = i - 128 * W1K - 128 * 128;
        const int n = j >> 7, k = j & 127;
        wt[i] = f2bf(W3[(size_t)k * 128 + n]);
    }
}

// ==================== node feature pre-conversion to bf16 tables ====================

#define NS_ELEMS (N_NODES * 64)
#define NV_ELEMS (N_NODES * 96)

__global__ __launch_bounds__(256)
void nodecvt_kernel(const float* __restrict__ ns, const float* __restrict__ nv,
                    u16* __restrict__ nsb, u16* __restrict__ nvb) {
    const int i2 = (blockIdx.x * 256 + threadIdx.x) * 2;
    if (i2 < NS_ELEMS) {
        float2 v = *(const float2*)(ns + i2);
        *(unsigned*)(nsb + i2) = cvtpk(v.x, v.y);
    } else if (i2 < NS_ELEMS + NV_ELEMS) {
        const int j2 = i2 - NS_ELEMS;
        float2 v = *(const float2*)(nv + j2);
        *(unsigned*)(nvb + j2) = cvtpk(v.x, v.y);
    }
}

// ==================== phase E: MLP + factored message epilogue, CSR-slot ordered ====================
// msg row [MROW=208 u16]: [0,32) m0 | [32,96) sg=s*gate | [96,192) m1b | [192,198) ev f32x3 | pad

__global__ __launch_bounds__(256, 4)
void mlp_msg_kernel(const u16* __restrict__ ns_bf,
                    const u16* __restrict__ nv_bf,
                    const float* __restrict__ edge_vec,
                    const float* __restrict__ sef,
                    const float* __restrict__ lengths,
                    const int* __restrict__ senders,
                    const int* __restrict__ receivers,
                    const int* __restrict__ elist,
                    const u16* __restrict__ wt,
                    const float* __restrict__ b1,
                    const float* __restrict__ b2,
                    const float* __restrict__ b3,
                    u16* __restrict__ msg, int slo, int cnt)
{
    __shared__ u16 A [EB * AST];
    __shared__ u16 Hb[EB * HST];

    const int t = threadIdx.x;
    const int lbase = blockIdx.x * EB;
    const int me = t >> 2, q = t & 3;
    const int ls = lbase + me;
    const bool ve = ls < cnt;
    const int eid = ve ? elist[slo + ls] : 0;

    {   const int si = senders[eid];
        const int ri = receivers[eid];
        u16* Ar = A + me * AST;
        const u16* srow = ns_bf + (size_t)si * 64 + q * 16;
        const u16* rrow = ns_bf + (size_t)ri * 64 + q * 16;
        *(u16x8*)(Ar + q * 16)          = *(const u16x8*)(srow);
        *(u16x8*)(Ar + q * 16 + 8)      = *(const u16x8*)(srow + 8);
        *(u16x8*)(Ar + 64 + q * 16)     = *(const u16x8*)(rrow);
        *(u16x8*)(Ar + 64 + q * 16 + 8) = *(const u16x8*)(rrow + 8);
        stage8(sef + (size_t)eid * 32 + q * 8, Ar + 128 + q * 8, true);
        if (q == 0) {
            u16x8 z8 = (u16x8)0;
            z8[0] = f2bf(lengths[eid]);
            *(u16x8*)(Ar + 160) = z8;                 // len + zero cols 161..167
            const float evx = edge_vec[(size_t)eid * 3 + 0];
            const float evy = edge_vec[(size_t)eid * 3 + 1];
            const float evz = edge_vec[(size_t)eid * 3 + 2];
            const unsigned bx = __builtin_bit_cast(unsigned, evx);
            const unsigned by = __builtin_bit_cast(unsigned, evy);
            const unsigned bz = __builtin_bit_cast(unsigned, evz);
            u16x8 p;
            p[0] = (u16)(bx & 0xFFFF); p[1] = (u16)(bx >> 16);
            p[2] = (u16)(by & 0xFFFF); p[3] = (u16)(by >> 16);
            p[4] = (u16)(bz & 0xFFFF); p[5] = (u16)(bz >> 16);
            p[6] = (u16)si;            p[7] = 0;
            *(u16x8*)(Hb + me * HST + 128) = p;
        } else if (q == 1) {
            *(u16x8*)(A + me * AST + 168) = (u16x8)0; // zero cols 168..175
        }
    }
    __syncthreads();

    const int w  = t >> 6, l = t & 63;
    const int lr = l & 31;
    const int lg = l >> 5;
    const int m0 = (w >> 1) * 32;
    const int n0 = (w & 1) * 64;

    const u16* w1t = wt;
    const u16* w2t = wt + 128 * W1K;
    const u16* w3t = w2t + 128 * 128;

    f32x16 acc0, acc1;

    auto run_layer = [&](const u16* Asrc, int astr, const u16* Wg, int wstr, auto NS,
                         f32x16& a0, f32x16& a1) {
        #pragma unroll
        for (int i = 0; i < 16; ++i) { a0[i] = 0.f; a1[i] = 0.f; }
        const u16* ap  = Asrc + (m0 + lr) * astr + lg * 8;
        const u16* bp0 = Wg + (size_t)(n0 + lr) * wstr + lg * 8;
        const u16* bp1 = bp0 + 32 * wstr;
        #pragma unroll
        for (int ks = 0; ks < NS.val; ++ks) {
            bf16x8 af  = *(const bf16x8*)(ap  + ks * 16);
            bf16x8 bv0 = *(const bf16x8*)(bp0 + ks * 16);
            bf16x8 bv1 = *(const bf16x8*)(bp1 + ks * 16);
            a0 = __builtin_amdgcn_mfma_f32_32x32x16_bf16(af, bv0, a0, 0, 0, 0);
            a1 = __builtin_amdgcn_mfma_f32_32x32x16_bf16(af, bv1, a1, 0, 0, 0);
        }
    };

    // ---------- layer 1 ----------
    run_layer(A, AST, w1t, W1K, IC<11>{}, acc0, acc1);
    __syncthreads();   // all A-reads complete
    {   const float bv0 = b1[n0 + lr], bv1 = b1[n0 + 32 + lr];
        #pragma unroll
        for (int r = 0; r < 16; ++r) {
            const int row = (r & 3) + 8 * (r >> 2) + 4 * lg;
            Hb[(m0 + row) * HST + n0 + lr]      = f2bf(fsilu(acc0[r] + bv0));
            Hb[(m0 + row) * HST + n0 + 32 + lr] = f2bf(fsilu(acc1[r] + bv1));
        }
    }
    {   // stage v_snd (bf16 table) into A rows 64..159 (dead after layer 1)
        const int si2 = (int)Hb[me * HST + 134];
        const u16* src = nv_bf + (size_t)si2 * 96 + q * 24;
        u16* dst = A + me * AST + 64 + q * 24;
        *(u16x8*)(dst)      = *(const u16x8*)(src);
        *(u16x8*)(dst + 8)  = *(const u16x8*)(src + 8);
        *(u16x8*)(dst + 16) = *(const u16x8*)(src + 16);
    }
    __syncthreads();

    // ---------- layer 2 ----------
    run_layer(Hb, HST, w2t, 128, IC<8>{}, acc0, acc1);
    __syncthreads();
    {   const float bv0 = b2[n0 + lr], bv1 = b2[n0 + 32 + lr];
        #pragma unroll
        for (int r = 0; r < 16; ++r) {
            const int row = (r & 3) + 8 * (r >> 2) + 4 * lg;
            Hb[(m0 + row) * HST + n0 + lr]      = f2bf(fsilu(acc0[r] + bv0));
            Hb[(m0 + row) * HST + n0 + 32 + lr] = f2bf(fsilu(acc1[r] + bv1));
        }
    }
    __syncthreads();

    // ---------- layer 3 (mix) ----------
    run_layer(Hb, HST, w3t, 128, IC<8>{}, acc0, acc1);
    __syncthreads();
    {   const float bv0 = b3[n0 + lr], bv1 = b3[n0 + 32 + lr];
        #pragma unroll
        for (int r = 0; r < 16; ++r) {
            const int row = (r & 3) + 8 * (r >> 2) + 4 * lg;
            Hb[(m0 + row) * HST + n0 + lr]      = f2bf(acc0[r] + bv0);
            Hb[(m0 + row) * HST + n0 + 32 + lr] = f2bf(acc1[r] + bv1);
        }
    }
    __syncthreads();

    // ---------- factored message epilogue: 4 threads/edge ----------
    if (ve) {
        const u16* Ar = A  + me * AST;
        const u16* Vr = Ar + 64;
        const u16* Hr = Hb + me * HST;
        const u16* Er = Hr + 128;
        u16* mrow = msg + (size_t)ls * MROW;
        const float evx = __builtin_bit_cast(float, (unsigned)Er[0] | ((unsigned)Er[1] << 16));
        const float evy = __builtin_bit_cast(float, (unsigned)Er[2] | ((unsigned)Er[3] << 16));
        const float evz = __builtin_bit_cast(float, (unsigned)Er[4] | ((unsigned)Er[5] << 16));

        // m0 (cols 8q..8q+7) and m1b (c=8q..8q+7) share v[c]
        float m0v[8], m1bv[24];
        #pragma unroll
        for (int j = 0; j < 8; ++j) {
            const int c = 8 * q + j;
            const float vx = bf2f(Vr[3 * c]), vy = bf2f(Vr[3 * c + 1]), vz = bf2f(Vr[3 * c + 2]);
            m0v[j] = (vx * evx + vy * evy + vz * evz) * INV_SQ3 * bf2f(Hr[c]);
            const float gb = bf2f(Hr[96 + c]) * INV_SQ2;
            m1bv[3 * j + 0] = (vy * evz - vz * evy) * gb;
            m1bv[3 * j + 1] = (vz * evx - vx * evz) * gb;
            m1bv[3 * j + 2] = (vx * evy - vy * evx) * gb;
        }
        {   uint4 o = { cvtpk(m0v[0], m0v[1]), cvtpk(m0v[2], m0v[3]),
                        cvtpk(m0v[4], m0v[5]), cvtpk(m0v[6], m0v[7]) };
            *(uint4*)(mrow + 8 * q) = o;
        }
        {   u16* dst = mrow + 96 + 24 * q;
            uint4 o0 = { cvtpk(m1bv[0],  m1bv[1]),  cvtpk(m1bv[2],  m1bv[3]),
                         cvtpk(m1bv[4],  m1bv[5]),  cvtpk(m1bv[6],  m1bv[7])  };
            uint4 o1 = { cvtpk(m1bv[8],  m1bv[9]),  cvtpk(m1bv[10], m1bv[11]),
                         cvtpk(m1bv[12], m1bv[13]), cvtpk(m1bv[14], m1bv[15]) };
            uint4 o2 = { cvtpk(m1bv[16], m1bv[17]), cvtpk(m1bv[18], m1bv[19]),
                         cvtpk(m1bv[20], m1bv[21]), cvtpk(m1bv[22], m1bv[23]) };
            *(uint4*)(dst)      = o0;
            *(uint4*)(dst + 8)  = o1;
            *(uint4*)(dst + 16) = o2;
        }
        // sg[k] = s[k] * gate[32+k], k = 16q..16q+15
        {   float sg[16];
            #pragma unroll
            for (int j = 0; j < 16; ++j) {
                const int k = 16 * q + j;
                sg[j] = bf2f(Ar[k]) * bf2f(Hr[32 + k]);
            }
            u16* dst = mrow + 32 + 16 * q;
            uint4 o0 = { cvtpk(sg[0],  sg[1]),  cvtpk(sg[2],  sg[3]),
                         cvtpk(sg[4],  sg[5]),  cvtpk(sg[6],  sg[7])  };
            uint4 o1 = { cvtpk(sg[8],  sg[9]),  cvtpk(sg[10], sg[11]),
                         cvtpk(sg[12], sg[13]), cvtpk(sg[14], sg[15]) };
            *(uint4*)(dst)     = o0;
            *(uint4*)(dst + 8) = o1;
        }
        if (q == 0) {
            uint4 e4 = { __builtin_bit_cast(unsigned, evx),
                         __builtin_bit_cast(unsigned, evy),
                         __builtin_bit_cast(unsigned, evz), 0u };
            *(uint4*)(mrow + 192) = e4;
            uint4 z4 = { 0u, 0u, 0u, 0u };
            *(uint4*)(mrow + 200) = z4;
        }
    }
}

// ==================== phase 2: paired streaming gather with rank-1 expansion ====================
// wave per node; lanes 0-25 edge j, lanes 26-51 edge j+1; LDS redistribution.

__global__ __launch_bounds__(256)
void msg_gather_seq(const int* __restrict__ rowp,
                    const u16* __restrict__ msg,
                    float* __restrict__ out,
                    int slo, int shi, int first)
{
    __shared__ float oacc[4][OUTC];

    const int gw = (blockIdx.x * 256 + threadIdx.x) >> 6;   // node
    const int l  = threadIdx.x & 63;
    const bool nvalid = gw < N_NODES;

    const int rp0 = nvalid ? rowp[gw] : 0;
    const int rp1 = nvalid ? rowp[gw + 1] : 0;
    const int lo = rp0 > slo ? rp0 : slo;
    const int hi = rp1 < shi ? rp1 : shi;
    const int n  = hi > lo ? hi - lo : 0;

    const int half = (l >= 26) ? 1 : 0;
    const int sl   = l - 26 * half;
    const bool lact = (l < 52) && (sl < 24);
    const int seg  = (sl < 4) ? 0 : (sl < 12 ? 1 : 2);

    float acc[24];
    #pragma unroll
    for (int i = 0; i < 24; ++i) acc[i] = 0.f;

    const u16* mb = msg + (size_t)(lo - slo) * MROW;

    auto body = [&](int row) {
        const u16* rp = mb + (size_t)row * MROW + sl * 8;
        const u16x8 v = *(const u16x8*)rp;
        if (seg == 1) {
            const float4 e4 = *(const float4*)(mb + (size_t)row * MROW + 192);
            #pragma unroll
            for (int i = 0; i < 8; ++i) {
                const float s = bf2f(v[i]);
                acc[3 * i + 0] += s * e4.x;
                acc[3 * i + 1] += s * e4.y;
                acc[3 * i + 2] += s * e4.z;
            }
        } else {
            #pragma unroll
            for (int i = 0; i < 8; ++i) acc[i] += bf2f(v[i]);
        }
    };

    int j = 0;
    for (; j + 2 <= n; j += 2) {
        if (lact) body(j + half);
    }
    if (j < n && half == 0 && lact) body(j);

    float* oa = oacc[(threadIdx.x >> 6)];

    // step1: half0 lanes write (full coverage of 320 cols)
    if (half == 0 && lact) {
        if (seg == 0) {
            #pragma unroll
            for (int i = 0; i < 8; ++i) oa[sl * 8 + i] = acc[i];
        } else if (seg == 1) {
            const int k0 = (sl - 4) * 8;
            #pragma unroll
            for (int i = 0; i < 8; ++i) {
                oa[32 + 3 * (k0 + i) + 0] = acc[3 * i + 0];
                oa[32 + 3 * (k0 + i) + 1] = acc[3 * i + 1];
                oa[32 + 3 * (k0 + i) + 2] = acc[3 * i + 2];
            }
        } else {
            const int c0 = (sl - 12) * 8;
            #pragma unroll
            for (int i = 0; i < 8; ++i) oa[224 + c0 + i] = acc[i];
        }
    }
    __syncthreads();
    // step2: half1 lanes add
    if (half == 1 && lact) {
        if (seg == 0) {
            #pragma unroll
            for (int i = 0; i < 8; ++i) oa[sl * 8 + i] += acc[i];
        } else if (seg == 1) {
            const int k0 = (sl - 4) * 8;
            #pragma unroll
            for (int i = 0; i < 8; ++i) {
                oa[32 + 3 * (k0 + i) + 0] += acc[3 * i + 0];
                oa[32 + 3 * (k0 + i) + 1] += acc[3 * i + 1];
                oa[32 + 3 * (k0 + i) + 2] += acc[3 * i + 2];
            }
        } else {
            const int c0 = (sl - 12) * 8;
            #pragma unroll
            for (int i = 0; i < 8; ++i) oa[224 + c0 + i] += acc[i];
        }
    }
    __syncthreads();

    if (nvalid && l < 40) {
        float r[8];
        #pragma unroll
        for (int i = 0; i < 8; ++i) r[i] = oa[l * 8 + i] * INV_AVG;
        float* orow = out + (size_t)gw * OUTC + l * 8;
        if (first) {
            *(float4*)(orow)     = make_float4(r[0], r[1], r[2], r[3]);
            *(float4*)(orow + 4) = make_float4(r[4], r[5], r[6], r[7]);
        } else if (n > 0) {
            float4 p0 = *(const float4*)(orow);
            float4 p1 = *(const float4*)(orow + 4);
            p0.x += r[0]; p0.y += r[1]; p0.z += r[2]; p0.w += r[3];
            p1.x += r[4]; p1.y += r[5]; p1.z += r[6]; p1.w += r[7];
            *(float4*)(orow)     = p0;
            *(float4*)(orow + 4) = p1;
        }
    }
}

// ==================== last-resort fallback: atomic fused ====================

__global__ __launch_bounds__(256, 2)
void fused_mpconv_atomic(const float* __restrict__ node_scalars,
                         const float* __restrict__ node_vectors,
                         const float* __restrict__ edge_vec,
                         const float* __restrict__ sef,
                         const float* __restrict__ lengths,
                         const int* __restrict__ senders,
                         const int* __restrict__ receivers,
                         const float* __restrict__ W1, const float* __restrict__ b1,
                         const float* __restrict__ W2, const float* __restrict__ b2,
                         const float* __restrict__ W3, const float* __restrict__ b3,
                         float* __restrict__ out)
{
    __shared__ u16 A [EB * KP1];
    __shared__ u16 VS[EB * KV];
    __shared__ u16 Hb[EB * KH];
    __shared__ u16 Wt[2][128 * WTS];
    __shared__ float evl[3][EB];
    __shared__ int sidx[EB], ridx[EB];

    const int t = threadIdx.x;
    const int ebase = blockIdx.x * EB;

    {   const int e = t & 63, sub = t >> 6;
        const int eg = ebase + e; const bool ve = eg < N_EDGES;
        if (sub == 0)      sidx[e] = ve ? senders[eg] : 0;
        else if (sub == 1) ridx[e] = ve ? receivers[eg] : 0;
        else if (sub == 2) {
            evl[0][e] = ve ? edge_vec[(size_t)eg * 3 + 0] : 0.f;
            evl[1][e] = ve ? edge_vec[(size_t)eg * 3 + 1] : 0.f;
            evl[2][e] = ve ? edge_vec[(size_t)eg * 3 + 2] : 0.f;
        }
    }
    __syncthreads();

    {   const int me = t >> 2, q = t & 3;
        const int eg = ebase + me; const bool ve = eg < N_EDGES;
        const int si = sidx[me], ri = ridx[me];
        u16* Ar = A + me * KP1;
        stage16(node_scalars + (size_t)si * 64 + q * 16, Ar + q * 16,       ve);
        stage16(node_scalars + (size_t)ri * 64 + q * 16, Ar + 64 + q * 16,  ve);
        stage8 (sef          + (size_t)eg * 32 + q * 8,  Ar + 128 + q * 8,  ve);
        u16x8 zz = (u16x8)0;
        *(u16x8*)(Ar + 160 + q * 8) = zz;
        if (q == 0) *(u16x8*)(Ar + 192) = zz;
        stage16(node_vectors + (size_t)si * 96 + q * 24,      VS + me * KV + q * 24,      ve);
        stage8 (node_vectors + (size_t)si * 96 + q * 24 + 16, VS + me * KV + q * 24 + 16, ve);
        if (q == 0) Ar[160] = f2bf(ve ? lengths[eg] : 0.f);
    }
    __syncthreads();

    const int w  = t >> 6, l = t & 63;
    const int lr = l & 31;
    const int lg = l >> 5;
    const int m0 = (w >> 1) * 32;
    const int n0 = (w & 1) * 64;

    f32x16 acc0, acc1;
    const int n  = t & 127, ph = t >> 7;

    auto run_layer = [&](const u16* Asrc, int astr, const float* Wg, int Kr, int nsteps,
                         f32x16& a0, f32x16& a1) {
        #pragma unroll
        for (int i = 0; i < 16; ++i) { a0[i] = 0.f; a1[i] = 0.f; }
        #pragma unroll
        for (int i = 0; i < 4; ++i) {
            int kl = (i * 2 + ph) * 2;
            float v0 = (kl     < Kr) ? Wg[(size_t)kl * 128 + n]       : 0.f;
            float v1 = (kl + 1 < Kr) ? Wg[(size_t)(kl + 1) * 128 + n] : 0.f;
            *(unsigned*)&Wt[0][n * WTS + kl] = cvtpk(v0, v1);
        }
        __syncthreads();
        const u16* ap = Asrc + (m0 + lr) * astr + lg * 8;
        for (int ks = 0; ks < nsteps; ++ks) {
            const int cur = ks & 1;
            float v0[4], v1[4];
            const int kb = (ks + 1) * 16;
            if (ks + 1 < nsteps) {
                #pragma unroll
                for (int i = 0; i < 4; ++i) {
                    int kg = kb + (i * 2 + ph) * 2;
                    v0[i] = (kg     < Kr) ? Wg[(size_t)kg * 128 + n]       : 0.f;
                    v1[i] = (kg + 1 < Kr) ? Wg[(size_t)(kg + 1) * 128 + n] : 0.f;
                }
            }
            bf16x8 af = *(const bf16x8*)(ap + ks * 16);
            bf16x8 bf0 = *(const bf16x8*)(&Wt[cur][(n0      + lr) * WTS + lg * 8]);
            bf16x8 bf1 = *(const bf16x8*)(&Wt[cur][(n0 + 32 + lr) * WTS + lg * 8]);
            a0 = __builtin_amdgcn_mfma_f32_32x32x16_bf16(af, bf0, a0, 0, 0, 0);
            a1 = __builtin_amdgcn_mfma_f32_32x32x16_bf16(af, bf1, a1, 0, 0, 0);
            if (ks + 1 < nsteps) {
                #pragma unroll
                for (int i = 0; i < 4; ++i) {
                    int kl = (i * 2 + ph) * 2;
                    *(unsigned*)&Wt[cur ^ 1][n * WTS + kl] = cvtpk(v0[i], v1[i]);
                }
            }
            __syncthreads();
        }
    };

    run_layer(A, KP1, W1, 161, 11, acc0, acc1);
    {   const float bv0 = b1[n0 + lr], bv1 = b1[n0 + 32 + lr];
        #pragma unroll
        for (int r = 0; r < 16; ++r) {
            const int row = (r & 3) + 8 * (r >> 2) + 4 * lg;
            Hb[(m0 + row) * KH + n0 + lr]      = f2bf(fsilu(acc0[r] + bv0));
            Hb[(m0 + row) * KH + n0 + 32 + lr] = f2bf(fsilu(acc1[r] + bv1));
        }
    }
    __syncthreads();

    run_layer(Hb, KH, W2, 128, 8, acc0, acc1);
    __syncthreads();
    {   const float bv0 = b2[n0 + lr], bv1 = b2[n0 + 32 + lr];
        #pragma unroll
        for (int r = 0; r < 16; ++r) {
            const int row = (r & 3) + 8 * (r >> 2) + 4 * lg;
            Hb[(m0 + row) * KH + n0 + lr]      = f2bf(fsilu(acc0[r] + bv0));
            Hb[(m0 + row) * KH + n0 + 32 + lr] = f2bf(fsilu(acc1[r] + bv1));
        }
    }
    __syncthreads();

    run_layer(Hb, KH, W3, 128, 8, acc0, acc1);
    __syncthreads();
    {   const float bv0 = b3[n0 + lr], bv1 = b3[n0 + 32 + lr];
        #pragma unroll
        for (int r = 0; r < 16; ++r) {
            const int row = (r & 3) + 8 * (r >> 2) + 4 * lg;
            Hb[(m0 + row) * KH + n0 + lr]      = f2bf(acc0[r] + bv0);
            Hb[(m0 + row) * KH + n0 + 32 + lr] = f2bf(acc1[r] + bv1);
        }
    }
    __syncthreads();

    {   const int me = t >> 2, r = t & 3;
        const int eg2 = ebase + me;
        if (eg2 < N_EDGES) {
            const int row = ridx[me];
            const float evx = evl[0][me], evy = evl[1][me], evz = evl[2][me];
            float* orow = out + (size_t)row * OUTC;
            const u16* Ar = A  + me * KP1;
            const u16* Vr = VS + me * KV;
            const u16* Hr = Hb + me * KH;
            for (int col = r; col < OUTC; col += 4) {
                float val;
                if (col < 32) {
                    const int c = col;
                    const float vx = bf2f(Vr[3 * c]), vy = bf2f(Vr[3 * c + 1]), vz = bf2f(Vr[3 * c + 2]);
                    val = (vx * evx + vy * evy + vz * evz) * INV_SQ3 * bf2f(Hr[c]);
                } else {
                    const int idx = col - 32;
                    const int k = idx / 3;
                    const int d = idx - 3 * k;
                    const float g = bf2f(Hr[32 + k]);
                    if (k < 64) {
                        const float evd = (d == 0) ? evx : ((d == 1) ? evy : evz);
                        val = bf2f(Ar[k]) * evd * g;
                    } else {
                        const int c = k - 64;
                        const float vx = bf2f(Vr[3 * c]), vy = bf2f(Vr[3 * c + 1]), vz = bf2f(Vr[3 * c + 2]);
                        float cr;
                        if (d == 0)      cr = vy * evz - vz * evy;
                        else if (d == 1) cr = vz * evx - vx * evz;
                        else             cr = vx * evy - vy * evx;
                        val = cr * INV_SQ2 * g;
                    }
                }
                atomicAdd(&orow[col], val * INV_AVG);
            }
        }
    }
}

// ==================== launch ====================

extern "C" void kernel_launch(void* const* d_in, const int* in_sizes, int n_in,
                              void* d_out, int out_size, void* d_ws, size_t ws_size,
                              hipStream_t stream) {
    (void)in_sizes; (void)n_in;
    const float* node_scalars = (const float*)d_in[0];
    const float* node_vectors = (const float*)d_in[1];
    const float* edge_vec     = (const float*)d_in[2];
    const float* sef          = (const float*)d_in[3];
    const float* lengths      = (const float*)d_in[4];
    const int*   senders      = (const int*)d_in[5];
    const int*   receivers    = (const int*)d_in[6];
    const float* W1 = (const float*)d_in[7];
    const float* b1 = (const float*)d_in[8];
    const float* W2 = (const float*)d_in[9];
    const float* b2 = (const float*)d_in[10];
    const float* W3 = (const float*)d_in[11];
    const float* b3 = (const float*)d_in[12];
    float* out = (float*)d_out;

    auto align256 = [](size_t x) { return (x + 255) & ~(size_t)255; };

    size_t off = 0;
    const size_t o_counts  = off; off += align256((size_t)N_NODES * sizeof(int));
    const size_t o_rowp    = off; off += align256((size_t)(N_NODES + 1) * sizeof(int));
    const size_t o_cursors = off; off += align256((size_t)(N_NODES + 1) * sizeof(int));
    const size_t o_part    = off; off += align256(64 * sizeof(int));
    const size_t o_elist   = off; off += align256((size_t)N_EDGES * sizeof(int));
    const size_t o_wt      = off; off += align256((size_t)WT_TOTAL * sizeof(u16));
    const size_t o_nsb     = off; off += align256((size_t)NS_ELEMS * sizeof(u16));
    const size_t o_nvb     = off; off += align256((size_t)NV_ELEMS * sizeof(u16));
    const size_t o_msg     = off;
    const size_t fixed_bytes = off;

    const size_t ROWB = (size_t)MROW * sizeof(u16);   // 416
    long Ec = 0;
    if (ws_size > fixed_bytes + (size_t)128 * ROWB) {
        size_t cap_rows = (ws_size - fixed_bytes) / ROWB;
        Ec = ((long)cap_rows - 64) / 64 * 64;
        if (Ec > N_EDGES) Ec = N_EDGES;
    }

    char* ws = (char*)d_ws;

    if (Ec >= 64) {
        int* counts  = (int*)(ws + o_counts);
        int* rowp    = (int*)(ws + o_rowp);
        int* cursors = (int*)(ws + o_cursors);
        int* part    = (int*)(ws + o_part);
        int* elist   = (int*)(ws + o_elist);
        u16* wt      = (u16*)(ws + o_wt);
        u16* nsb     = (u16*)(ws + o_nsb);
        u16* nvb     = (u16*)(ws + o_nvb);
        u16* msg     = (u16*)(ws + o_msg);

        hipMemsetAsync(counts, 0, (size_t)N_NODES * sizeof(int), stream);
        hist_kernel<<<(N_EDGES + 255) / 256, 256, 0, stream>>>(receivers, counts);
        scan_k1<<<NBLK1, 256, 0, stream>>>(counts, rowp, part);
        scan_k2<<<1, 64, 0, stream>>>(part);
        scan_k3<<<NBLK1, 256, 0, stream>>>(rowp, part, cursors);
        fill_kernel<<<(N_EDGES + 255) / 256, 256, 0, stream>>>(receivers, cursors, elist);
        wcvt_kernel<<<(WT_TOTAL + 255) / 256, 256, 0, stream>>>(W1, W2, W3, wt);
        nodecvt_kernel<<<((NS_ELEMS + NV_ELEMS) / 2 + 255) / 256, 256, 0, stream>>>(
            node_scalars, node_vectors, nsb, nvb);

        const int nchunks = (int)((N_EDGES + Ec - 1) / Ec);
        const int ggrid = (N_NODES * 64 + 255) / 256;
        for (int c = 0; c < nchunks; ++c) {
            const int slo = (int)(c * Ec);
            const int cnt = (int)((N_EDGES - slo < Ec) ? (N_EDGES - slo) : Ec);
            mlp_msg_kernel<<<(cnt + EB - 1) / EB, 256, 0, stream>>>(
                nsb, nvb, edge_vec, sef, lengths, senders, receivers,
                elist, wt, b1, b2, b3, msg, slo, cnt);
            msg_gather_seq<<<ggrid, 256, 0, stream>>>(
                rowp, msg, out, slo, slo + cnt, c == 0 ? 1 : 0);
        }
    } else {
        hipMemsetAsync(out, 0, (size_t)out_size * sizeof(float), stream);
        fused_mpconv_atomic<<<(N_EDGES + EB - 1) / EB, 256, 0, stream>>>(
            node_scalars, node_vectors, edge_vec, sef, lengths,
            senders, receivers, W1, b1, W2, b2, W3, b3, out);
    }
}